// Round 12
// baseline (3331.733 us; speedup 1.0000x reference)
//
#include <hip/hip_runtime.h>
#include <hip/hip_bf16.h>

#define D_MODEL 2048
#define NH 32
#define HDIM 64
#define KVHEADS 8
#define DKV 512
#define DFF 8192
#define SEQ 1024
#define BATCH 4
#define NTOK 4096
#define VOCAB 32000
#define NLAYER 4

typedef __attribute__((ext_vector_type(8))) _Float16 f16x8;
typedef __attribute__((ext_vector_type(4))) _Float16 f16x4;
typedef __attribute__((ext_vector_type(4))) float f32x4;

static __device__ __forceinline__ void gload16(const void* g, void* l){
    __builtin_amdgcn_global_load_lds(
        (const __attribute__((address_space(1))) unsigned int*)g,
        (__attribute__((address_space(3))) unsigned int*)l, 16, 0, 0);
}

#define MFMA(d, x, y) d = __builtin_amdgcn_mfma_f32_16x16x32_f16(x, y, d, 0, 0, 0)
#define BAR()    __builtin_amdgcn_s_barrier()
#define LGK0()   do{ asm volatile("s_waitcnt lgkmcnt(0)" ::: "memory"); \
                     __builtin_amdgcn_sched_barrier(0); }while(0)
#define PRIO(x)  __builtin_amdgcn_s_setprio(x)

// ---------------- embedding gather ----------------
__global__ __launch_bounds__(256)
void gather_kernel(const int* __restrict__ tok, const float* __restrict__ embed,
                   float* __restrict__ X)
{
    int row = blockIdx.x;
    int id = tok[row];
    const float4* s = (const float4*)(embed + (size_t)id * D_MODEL);
    float4* d = (float4*)(X + (size_t)row * D_MODEL);
    d[threadIdx.x]       = s[threadIdx.x];
    d[threadIdx.x + 256] = s[threadIdx.x + 256];
}

// ---------------- rope cos/sin table: rt[pos*32+d] = {cos, sin} ----------------
__global__ __launch_bounds__(256)
void rope_table_kernel(float2* __restrict__ rt)
{
    int idx = blockIdx.x * 256 + threadIdx.x;   // 1024*32
    int pos = idx >> 5, d = idx & 31;
    float inv = powf(500000.0f, -(float)d * (1.0f / 32.0f));
    float ang = (float)pos * inv;
    float s, c;
    sincosf(ang, &s, &c);
    rt[idx] = make_float2(c, s);
}

// ---------------- weight convert: all 7 matrices of one layer, 1 dispatch ------
__global__ __launch_bounds__(256)
void wconv_all_kernel(const int* __restrict__ wq, const int* __restrict__ wk,
                      const int* __restrict__ wv, const int* __restrict__ wo,
                      const int* __restrict__ wg, const int* __restrict__ wu,
                      const int* __restrict__ wd, _Float16* __restrict__ O)
{
    int i = blockIdx.x * 256 + threadIdx.x;   // vec index, total 15204352
    const int* s; int loc;
    if      (i <  1048576){ s = wq; loc = i; }
    else if (i <  1310720){ s = wk; loc = i - 1048576; }
    else if (i <  1572864){ s = wv; loc = i - 1310720; }
    else if (i <  2621440){ s = wo; loc = i - 1572864; }
    else if (i <  6815744){ s = wg; loc = i - 2621440; }
    else if (i < 11010048){ s = wu; loc = i - 6815744; }
    else                  { s = wd; loc = i - 11010048; }
    int4 w = ((const int4*)s)[loc];
    f16x4 o;
    o.x = (_Float16)(float)w.x; o.y = (_Float16)(float)w.y;
    o.z = (_Float16)(float)w.z; o.w = (_Float16)(float)w.w;
    ((f16x4*)O)[i] = o;
}

// ---------------- rmsnorm (fp32 in, fp16 out) ----------------
__global__ __launch_bounds__(256)
void rmsnorm_kernel(const float* __restrict__ X, const float* __restrict__ gamma,
                    _Float16* __restrict__ O)
{
    int row = blockIdx.x;
    const float* x = X + (size_t)row * D_MODEL;
    _Float16* o = O + (size_t)row * D_MODEL;
    int t = threadIdx.x;
    float4 v[2];
    float ss = 0.f;
#pragma unroll
    for (int i = 0; i < 2; i++){
        v[i] = *(const float4*)&x[(t + i*256)*4];
        ss += v[i].x*v[i].x + v[i].y*v[i].y + v[i].z*v[i].z + v[i].w*v[i].w;
    }
    for (int off = 32; off; off >>= 1) ss += __shfl_xor(ss, off, 64);
    __shared__ float red[4];
    __shared__ float invs;
    int lane = t & 63, wid = t >> 6;
    if (lane == 0) red[wid] = ss;
    __syncthreads();
    if (t == 0){
        float s = red[0] + red[1] + red[2] + red[3];
        invs = 1.0f / sqrtf(s / (float)D_MODEL + 1e-5f);
    }
    __syncthreads();
    float inv = invs;
#pragma unroll
    for (int i = 0; i < 2; i++){
        float4 g = *(const float4*)&gamma[(t + i*256)*4];
        f16x4 r;
        r.x = (_Float16)(v[i].x * inv * g.x); r.y = (_Float16)(v[i].y * inv * g.y);
        r.z = (_Float16)(v[i].z * inv * g.z); r.w = (_Float16)(v[i].w * inv * g.w);
        *(f16x4*)&o[(t + i*256)*4] = r;
    }
}

// final norm (fp32 out), last token per batch
__global__ __launch_bounds__(256)
void final_norm_kernel(const float* __restrict__ X, const float* __restrict__ gamma,
                       float* __restrict__ XF)
{
    int b = blockIdx.x;
    const float* x = X + ((size_t)b * SEQ + SEQ - 1) * D_MODEL;
    float* o = XF + (size_t)b * D_MODEL;
    int t = threadIdx.x;
    float4 v[2];
    float ss = 0.f;
#pragma unroll
    for (int i = 0; i < 2; i++){
        v[i] = *(const float4*)&x[(t + i*256)*4];
        ss += v[i].x*v[i].x + v[i].y*v[i].y + v[i].z*v[i].z + v[i].w*v[i].w;
    }
    for (int off = 32; off; off >>= 1) ss += __shfl_xor(ss, off, 64);
    __shared__ float red[4];
    __shared__ float invs;
    int lane = t & 63, wid = t >> 6;
    if (lane == 0) red[wid] = ss;
    __syncthreads();
    if (t == 0){
        float s = red[0] + red[1] + red[2] + red[3];
        invs = 1.0f / sqrtf(s / (float)D_MODEL + 1e-5f);
    }
    __syncthreads();
    float inv = invs;
#pragma unroll
    for (int i = 0; i < 2; i++){
        float4 g = *(const float4*)&gamma[(t + i*256)*4];
        float4 r;
        r.x = v[i].x * inv * g.x; r.y = v[i].y * inv * g.y;
        r.z = v[i].z * inv * g.z; r.w = v[i].w * inv * g.w;
        *(float4*)&o[(t + i*256)*4] = r;
    }
}

// ================= fused MLP GEMM: U = silu(A@Wg^T*sg) * (A@Wu^T*su) =========
// R6 texture; U tri-buffered (LDS 160KB total), uniform 2-gload staging per
// phase, counted vmcnt(4) per K-tile (U/G staged 2 tiles ahead).
__global__ __launch_bounds__(512, 1)
void gemm_mlp(const _Float16* __restrict__ A, const _Float16* __restrict__ WU,
              const _Float16* __restrict__ WG,
              const float* __restrict__ su, const float* __restrict__ sg,
              _Float16* __restrict__ U, int MT, int NT, int K)
{
    __shared__ __align__(16) _Float16 AS[2][256 * 64];
    __shared__ __align__(16) _Float16 US[3][128 * 64];
    __shared__ __align__(16) _Float16 GS[3][128 * 64];

    int nwg = MT * NT;
    int flat = blockIdx.x;
    int q = nwg >> 3, r = nwg & 7;
    int xcd = flat & 7, lid = flat >> 3;
    int swz = (xcd < r ? xcd * (q + 1) : r * (q + 1) + (xcd - r) * q) + lid;
    int bm = swz % MT, bn = swz / MT;
    int m0 = bm * 256, n0 = bn * 128;

    const int t = threadIdx.x;
    const int lane = t & 63, wid = t >> 6;
    const int ln15 = lane & 15, lq = lane >> 4;
    const int wm = wid >> 1, wn = wid & 1;   // 4 x 2 wave grid
    const int sw = ln15 & 7;
    const int sl0 = (lq ^ sw) * 8, sl1 = ((4 + lq) ^ sw) * 8;

    const _Float16* srcA[4]; const _Float16* srcU[2]; const _Float16* srcG[2];
#pragma unroll
    for (int rr = 0; rr < 4; rr++){
        int ch = rr * 512 + t;
        int row = ch >> 3, s = (ch & 7) ^ (row & 7);
        srcA[rr] = A + (size_t)(m0 + row) * K + s * 8;
    }
#pragma unroll
    for (int rr = 0; rr < 2; rr++){
        int ch = rr * 512 + t;
        int row = ch >> 3, s = (ch & 7) ^ (row & 7);
        srcU[rr] = WU + (size_t)(n0 + row) * K + s * 8;
        srcG[rr] = WG + (size_t)(n0 + row) * K + s * 8;
    }
#define STG_A2a(tile) do{ int _b = (tile) & 1; \
    gload16(srcA[0] + (size_t)(tile)*64, &AS[_b][(wid*64)*8]); \
    gload16(srcA[1] + (size_t)(tile)*64, &AS[_b][(512 + wid*64)*8]); }while(0)
#define STG_A2b(tile) do{ int _b = (tile) & 1; \
    gload16(srcA[2] + (size_t)(tile)*64, &AS[_b][(1024 + wid*64)*8]); \
    gload16(srcA[3] + (size_t)(tile)*64, &AS[_b][(1536 + wid*64)*8]); }while(0)
#define STG_U2(tile) do{ int _b = (tile) % 3; \
    gload16(srcU[0] + (size_t)(tile)*64, &US[_b][(wid*64)*8]); \
    gload16(srcU[1] + (size_t)(tile)*64, &US[_b][(512 + wid*64)*8]); }while(0)
#define STG_G2(tile) do{ int _b = (tile) % 3; \
    gload16(srcG[0] + (size_t)(tile)*64, &GS[_b][(wid*64)*8]); \
    gload16(srcG[1] + (size_t)(tile)*64, &GS[_b][(512 + wid*64)*8]); }while(0)

    f32x4 accU[4][4], accG[4][4];
#pragma unroll
    for (int i = 0; i < 4; i++)
#pragma unroll
        for (int j = 0; j < 4; j++){
            accU[i][j] = (f32x4){0.f, 0.f, 0.f, 0.f};
            accG[i][j] = (f32x4){0.f, 0.f, 0.f, 0.f};
        }

    const int KT = K >> 6;   // 32

    // prologue: tile0 {A,U,G} first (8 loads), then U(1),G(1) (4 loads).
    // vmcnt(4) => tile-0 inputs landed; U(1)/G(1) stay in flight.
    STG_A2a(0); STG_A2b(0); STG_U2(0); STG_G2(0);
    STG_U2(1);  STG_G2(1);
    asm volatile("s_waitcnt vmcnt(4)" ::: "memory");
    BAR();

    for (int kt = 0; kt < KT; ++kt){
        int cur = kt & 1, w3 = kt % 3;
        const _Float16* Ac = AS[cur];
        const _Float16* Uc = US[w3];
        const _Float16* Gc = GS[w3];
        bool s1 = (kt + 1 < KT), s2 = (kt + 2 < KT);

        // ---- P1: read af k0 + bu k0 (8); stage A(kt+1) half a; MFMA U k0 (16)
        f16x8 afk0[4], afk1[4], buk0[4], buk1[4];
#pragma unroll
        for (int mf = 0; mf < 4; mf++)
            afk0[mf] = *(const f16x8*)&Ac[(wm * 64 + mf * 16 + ln15) * 64 + sl0];
#pragma unroll
        for (int nf = 0; nf < 4; nf++)
            buk0[nf] = *(const f16x8*)&Uc[(wn * 64 + nf * 16 + ln15) * 64 + sl0];
        if (s1) STG_A2a(kt + 1);
        BAR(); LGK0(); PRIO(1);
#pragma unroll
        for (int mf = 0; mf < 4; mf++)
#pragma unroll
            for (int nf = 0; nf < 4; nf++)
                MFMA(accU[mf][nf], afk0[mf], buk0[nf]);
        PRIO(0); BAR();

        // ---- P2: read af k1 + bu k1 (8); stage A(kt+1) half b; MFMA U k1 (16)
#pragma unroll
        for (int mf = 0; mf < 4; mf++)
            afk1[mf] = *(const f16x8*)&Ac[(wm * 64 + mf * 16 + ln15) * 64 + sl1];
#pragma unroll
        for (int nf = 0; nf < 4; nf++)
            buk1[nf] = *(const f16x8*)&Uc[(wn * 64 + nf * 16 + ln15) * 64 + sl1];
        if (s1) STG_A2b(kt + 1);
        BAR(); LGK0(); PRIO(1);
#pragma unroll
        for (int mf = 0; mf < 4; mf++)
#pragma unroll
            for (int nf = 0; nf < 4; nf++)
                MFMA(accU[mf][nf], afk1[mf], buk1[nf]);
        PRIO(0); BAR();

        // ---- P3: read bg k0 + bg k1 (8); stage U(kt+2); MFMA G k0 (16)
        f16x8 bgk0[4], bgk1[4];
#pragma unroll
        for (int nf = 0; nf < 4; nf++){
            bgk0[nf] = *(const f16x8*)&Gc[(wn * 64 + nf * 16 + ln15) * 64 + sl0];
            bgk1[nf] = *(const f16x8*)&Gc[(wn * 64 + nf * 16 + ln15) * 64 + sl1];
        }
        if (s2) STG_U2(kt + 2);
        BAR(); LGK0(); PRIO(1);
#pragma unroll
        for (int mf = 0; mf < 4; mf++)
#pragma unroll
            for (int nf = 0; nf < 4; nf++)
                MFMA(accG[mf][nf], afk0[mf], bgk0[nf]);
        PRIO(0); BAR();

        // ---- P4: no reads; stage G(kt+2); MFMA G k1 (16); counted vmcnt
        if (s2) STG_G2(kt + 2);
        PRIO(1);
#pragma unroll
        for (int mf = 0; mf < 4; mf++)
#pragma unroll
            for (int nf = 0; nf < 4; nf++)
                MFMA(accG[mf][nf], afk1[mf], bgk1[nf]);
        PRIO(0);
        if (s1){
            if (s2) asm volatile("s_waitcnt vmcnt(4)" ::: "memory");
            else    asm volatile("s_waitcnt vmcnt(0)" ::: "memory");
            BAR();
            __builtin_amdgcn_sched_barrier(0);
        }
    }
#undef STG_A2a
#undef STG_A2b
#undef STG_U2
#undef STG_G2

#pragma unroll
    for (int mf = 0; mf < 4; mf++){
        int rowb = m0 + wm * 64 + mf * 16 + lq * 4;
#pragma unroll
        for (int nf = 0; nf < 4; nf++){
            int colg = n0 + wn * 64 + nf * 16 + ln15;
            float scu = su[colg], scg = sg[colg];
#pragma unroll
            for (int rr2 = 0; rr2 < 4; rr2++){
                float uv = accU[mf][nf][rr2] * scu;
                float gv = accG[mf][nf][rr2] * scg;
                float sig = 1.0f / (1.0f + expf(-gv));
                U[(size_t)(rowb + rr2) * DFF + colg] = (_Float16)(gv * sig * uv);
            }
        }
    }
}

// ---- gemm_small: BM=128, BN=256, per-wave 64x64, A+B 3-buf, 3/3 staging ----
// EPI: 0 = store f16; 1 = fp32 +=; 3 = qkv scatter with fused RoPE (q,k)
template<int EPI>
__global__ __launch_bounds__(512, 2)
void gemm_small(const _Float16* __restrict__ A, const _Float16* __restrict__ W,
                const float* __restrict__ sc0, const float* __restrict__ sc1,
                const float* __restrict__ sc2,
                void* __restrict__ C0, void* __restrict__ C1, void* __restrict__ C2,
                const float2* __restrict__ rt,
                int MT, int NT, int N, int K)
{
    __shared__ __align__(16) _Float16 AS[3][128 * 64];
    __shared__ __align__(16) _Float16 BS[3][256 * 64];

    int nwg = MT * NT;
    int flat = blockIdx.x;
    int q = nwg >> 3, r = nwg & 7;
    int xcd = flat & 7, lid = flat >> 3;
    int swz = (xcd < r ? xcd * (q + 1) : r * (q + 1) + (xcd - r) * q) + lid;
    int bm = swz % MT, bn = swz / MT;
    int m0 = bm * 128, n0 = bn * 256;

    const int t = threadIdx.x;
    const int lane = t & 63, wid = t >> 6;
    const int ln15 = lane & 15, lq = lane >> 4;
    const int wm = wid >> 2, wn = wid & 3;
    const int sw = ln15 & 7;
    const int sl0 = (lq ^ sw) * 8, sl1 = ((4 + lq) ^ sw) * 8;

    const _Float16* srcA[2]; const _Float16* srcB[4];
#pragma unroll
    for (int rr = 0; rr < 2; rr++){
        int ch = rr * 512 + t;
        int row = ch >> 3, s = (ch & 7) ^ (row & 7);
        srcA[rr] = A + (size_t)(m0 + row) * K + s * 8;
    }
#pragma unroll
    for (int rr = 0; rr < 4; rr++){
        int ch = rr * 512 + t;
        int row = ch >> 3, s = (ch & 7) ^ (row & 7);
        srcB[rr] = W + (size_t)(n0 + row) * K + s * 8;
    }
#define STG_P1(tile) do{ int _b = (tile) % 3; \
    gload16(srcB[0] + (size_t)(tile)*64, &BS[_b][(wid*64)*8]); \
    gload16(srcB[1] + (size_t)(tile)*64, &BS[_b][(512 + wid*64)*8]); \
    gload16(srcA[0] + (size_t)(tile)*64, &AS[_b][(wid*64)*8]); }while(0)
#define STG_P2(tile) do{ int _b = (tile) % 3; \
    gload16(srcB[2] + (size_t)(tile)*64, &BS[_b][(1024 + wid*64)*8]); \
    gload16(srcB[3] + (size_t)(tile)*64, &BS[_b][(1536 + wid*64)*8]); \
    gload16(srcA[1] + (size_t)(tile)*64, &AS[_b][(512 + wid*64)*8]); }while(0)

    f32x4 acc[4][4];
#pragma unroll
    for (int i = 0; i < 4; i++)
#pragma unroll
        for (int j = 0; j < 4; j++) acc[i][j] = (f32x4){0.f, 0.f, 0.f, 0.f};

    const int KT = K >> 6;

    STG_P1(0); STG_P2(0); STG_P1(1); STG_P2(1);
    asm volatile("s_waitcnt vmcnt(6)" ::: "memory");
    BAR();

    for (int kt = 0; kt < KT; ++kt){
        int cur = kt % 3;
        const _Float16* Ac = AS[cur];
        const _Float16* Bc = BS[cur];
        bool s1 = (kt + 1 < KT), s2 = (kt + 2 < KT);

        // ---- P1: read af k0 (4) + b k0 (4); stage 3 of tile kt+2; MFMA k0
        f16x8 af0[4], af1[4], bk0[4], bk1[4];
#pragma unroll
        for (int mf = 0; mf < 4; mf++)
            af0[mf] = *(const f16x8*)&Ac[(wm * 64 + mf * 16 + ln15) * 64 + sl0];
#pragma unroll
        for (int nf = 0; nf < 4; nf++)
            bk0[nf] = *(const f16x8*)&Bc[(wn * 64 + nf * 16 + ln15) * 64 + sl0];
        if (s2) STG_P1(kt + 2);
        BAR(); LGK0(); PRIO(1);
#pragma unroll
        for (int mf = 0; mf < 4; mf++)
#pragma unroll
            for (int nf = 0; nf < 4; nf++)
                MFMA(acc[mf][nf], af0[mf], bk0[nf]);
        PRIO(0); BAR();

        // ---- P2: read af k1 (4) + b k1 (4); stage remaining 3; MFMA k1
#pragma unroll
        for (int mf = 0; mf < 4; mf++)
            af1[mf] = *(const f16x8*)&Ac[(wm * 64 + mf * 16 + ln15) * 64 + sl1];
#pragma unroll
        for (int nf = 0; nf < 4; nf++)
            bk1[nf] = *(const f16x8*)&Bc[(wn * 64 + nf * 16 + ln15) * 64 + sl1];
        if (s2) STG_P2(kt + 2);
        BAR(); LGK0(); PRIO(1);
#pragma unroll
        for (int mf = 0; mf < 4; mf++)
#pragma unroll
            for (int nf = 0; nf < 4; nf++)
                MFMA(acc[mf][nf], af1[mf], bk1[nf]);
        PRIO(0);
        if (s1){
            if (s2) asm volatile("s_waitcnt vmcnt(6)" ::: "memory");
            else    asm volatile("s_waitcnt vmcnt(0)" ::: "memory");
            BAR();
            __builtin_amdgcn_sched_barrier(0);
        }
    }
#undef STG_P1
#undef STG_P2

    if (EPI == 3){
        const float* sp; _Float16* dp; int nloc, nstr;
        if (n0 < 2048)      { sp = sc0; dp = (_Float16*)C0; nloc = n0;        nstr = 2048; }
        else if (n0 < 2560) { sp = sc1; dp = (_Float16*)C1; nloc = n0 - 2048; nstr = 512; }
        else                { sp = sc2; dp = (_Float16*)C2; nloc = n0 - 2560; nstr = 512; }
        bool dorope = (n0 < 2560);      // q and k get RoPE, v does not
        if (dorope){
            // wave's 64-col span == one head; pair (d, d+32) = frags (nf, nf+2)
#pragma unroll
            for (int mf = 0; mf < 4; mf++){
                int rowb = m0 + wm * 64 + mf * 16 + lq * 4;
#pragma unroll
                for (int nf = 0; nf < 2; nf++){
                    int colg = wn * 64 + nf * 16 + ln15;
                    int d = nf * 16 + ln15;          // 0..31
                    float s1v = sp[nloc + colg], s2v = sp[nloc + colg + 32];
#pragma unroll
                    for (int rr2 = 0; rr2 < 4; rr2++){
                        int row = rowb + rr2;
                        int pos = row & (SEQ - 1);
                        float2 cs = rt[pos * 32 + d];
                        float x1 = acc[mf][nf][rr2] * s1v;
                        float x2 = acc[mf][nf + 2][rr2] * s2v;
                        dp[(size_t)row * nstr + nloc + colg]      = (_Float16)(x1 * cs.x - x2 * cs.y);
                        dp[(size_t)row * nstr + nloc + colg + 32] = (_Float16)(x1 * cs.y + x2 * cs.x);
                    }
                }
            }
        } else {
#pragma unroll
            for (int mf = 0; mf < 4; mf++){
                int rowb = m0 + wm * 64 + mf * 16 + lq * 4;
#pragma unroll
                for (int nf = 0; nf < 4; nf++){
                    int colg = wn * 64 + nf * 16 + ln15;
                    float sc = sp[nloc + colg];
#pragma unroll
                    for (int rr2 = 0; rr2 < 4; rr2++)
                        dp[(size_t)(rowb + rr2) * nstr + nloc + colg] =
                            (_Float16)(acc[mf][nf][rr2] * sc);
                }
            }
        }
    } else {
#pragma unroll
        for (int mf = 0; mf < 4; mf++){
            int rowb = m0 + wm * 64 + mf * 16 + lq * 4;
#pragma unroll
            for (int nf = 0; nf < 4; nf++){
                int colg = n0 + wn * 64 + nf * 16 + ln15;
                float sc = sc0[colg];
#pragma unroll
                for (int rr2 = 0; rr2 < 4; rr2++){
                    size_t idx = (size_t)(rowb + rr2) * N + colg;
                    float val = acc[mf][nf][rr2] * sc;
                    if (EPI == 0){
                        ((_Float16*)C0)[idx] = (_Float16)val;
                    } else {
                        ((float*)C0)[idx] += val;
                    }
                }
            }
        }
    }
}

// ---------------- flash attention (causal, GQA 4:1, fp16) ----------------
// T14 async-split + CU-load-balanced qt decode.
__global__ __launch_bounds__(256)
void attn_kernel(const _Float16* __restrict__ Qb, const _Float16* __restrict__ Kb,
                 const _Float16* __restrict__ Vb, _Float16* __restrict__ Ob)
{
    int bid = blockIdx.x;
    int qt = bid >> 7, h = bid & 31, b = (bid >> 5) & 3;
    int kvh = h >> 2;
    int q0 = qt * 128;
    int t = threadIdx.x, lane = t & 63, wid = t >> 6;
    int ln15 = lane & 15, lq = lane >> 4;

    __shared__ __align__(16) _Float16 Ksm[64 * 72];
    __shared__ __align__(16) _Float16 Vt[64 * 72];
    __shared__ __align__(16) _Float16 Pl[128 * 72];

    f16x8 qf[2][2];
    int qrow_g = b * SEQ + q0 + wid * 32;
#pragma unroll
    for (int mf = 0; mf < 2; mf++)
#pragma unroll
        for (int dc = 0; dc < 2; dc++)
            qf[mf][dc] = *(const f16x8*)(Qb + (size_t)(qrow_g + mf * 16 + ln15) * D_MODEL
                                         + h * HDIM + dc * 32 + lq * 8);

    f32x4 outv[2][4];
#pragma unroll
    for (int i = 0; i < 2; i++)
#pragma unroll
        for (int j = 0; j < 4; j++) outv[i][j] = (f32x4){0.f, 0.f, 0.f, 0.f};
    float mrun[2][4], lrun[2][4];
#pragma unroll
    for (int i = 0; i < 2; i++)
#pragma unroll
        for (int r = 0; r < 4; r++){ mrun[i][r] = -1e30f; lrun[i][r] = 0.f; }

    int ntile = (q0 + 128) >> 6;
    int ld_row = (t + 0) >> 3, ld_c8 = t & 7;
    int ld_row1 = (t + 256) >> 3;

    f16x8 k8[2], v8[2];
    {
        size_t base0 = (size_t)(b * SEQ + ld_row) * DKV + kvh * HDIM + ld_c8 * 8;
        size_t base1 = (size_t)(b * SEQ + ld_row1) * DKV + kvh * HDIM + ld_c8 * 8;
        k8[0] = *(const f16x8*)&Kb[base0];  v8[0] = *(const f16x8*)&Vb[base0];
        k8[1] = *(const f16x8*)&Kb[base1];  v8[1] = *(const f16x8*)&Vb[base1];
    }

    for (int kt = 0; kt < ntile; kt++){
        __syncthreads();
#pragma unroll
        for (int i = 0; i < 2; i++){
            int row = (i == 0) ? ld_row : ld_row1;
            *(f16x8*)&Ksm[row * 72 + ld_c8 * 8] = k8[i];
#pragma unroll
            for (int j = 0; j < 8; j++)
                Vt[(ld_c8 * 8 + j) * 72 + row] = v8[i][j];
        }
        __syncthreads();

        if (kt + 1 < ntile){
            size_t base0 = (size_t)(b * SEQ + (kt + 1) * 64 + ld_row) * DKV + kvh * HDIM + ld_c8 * 8;
            size_t base1 = (size_t)(b * SEQ + (kt + 1) * 64 + ld_row1) * DKV + kvh * HDIM + ld_c8 * 8;
            k8[0] = *(const f16x8*)&Kb[base0];  v8[0] = *(const f16x8*)&Vb[base0];
            k8[1] = *(const f16x8*)&Kb[base1];  v8[1] = *(const f16x8*)&Vb[base1];
        }

#pragma unroll
        for (int mf = 0; mf < 2; mf++){
            f32x4 sa[4];
#pragma unroll
            for (int kvf = 0; kvf < 4; kvf++) sa[kvf] = (f32x4){0.f, 0.f, 0.f, 0.f};
#pragma unroll
            for (int kvf = 0; kvf < 4; kvf++)
#pragma unroll
                for (int dc = 0; dc < 2; dc++){
                    f16x8 kb = *(const f16x8*)&Ksm[(kvf * 16 + ln15) * 72 + dc * 32 + lq * 8];
                    sa[kvf] = __builtin_amdgcn_mfma_f32_16x16x32_f16(qf[mf][dc], kb, sa[kvf], 0, 0, 0);
                }
            int qbase = q0 + wid * 32 + mf * 16 + lq * 4;
            float rowmax[4] = {-1e30f, -1e30f, -1e30f, -1e30f};
#pragma unroll
            for (int kvf = 0; kvf < 4; kvf++){
                int kva = kt * 64 + kvf * 16 + ln15;
#pragma unroll
                for (int r = 0; r < 4; r++){
                    float sv = sa[kvf][r] * 0.125f;
                    if (kva > qbase + r) sv = -1e9f;
                    sa[kvf][r] = sv;
                    rowmax[r] = fmaxf(rowmax[r], sv);
                }
            }
#pragma unroll
            for (int r = 0; r < 4; r++){
                rowmax[r] = fmaxf(rowmax[r], __shfl_xor(rowmax[r], 1, 64));
                rowmax[r] = fmaxf(rowmax[r], __shfl_xor(rowmax[r], 2, 64));
                rowmax[r] = fmaxf(rowmax[r], __shfl_xor(rowmax[r], 4, 64));
                rowmax[r] = fmaxf(rowmax[r], __shfl_xor(rowmax[r], 8, 64));
            }
            float scl[4], rsum[4];
#pragma unroll
            for (int r = 0; r < 4; r++){
                float mo = mrun[mf][r];
                float mn = fmaxf(mo, rowmax[r]);
                scl[r] = expf(mo - mn);
                mrun[mf][r] = mn;
                rsum[r] = 0.f;
            }
#pragma unroll
            for (int kvf = 0; kvf < 4; kvf++)
#pragma unroll
                for (int r = 0; r < 4; r++){
                    float p = expf(sa[kvf][r] - mrun[mf][r]);
                    sa[kvf][r] = p;
                    rsum[r] += p;
                }
#pragma unroll
            for (int r = 0; r < 4; r++){
                rsum[r] += __shfl_xor(rsum[r], 1, 64);
                rsum[r] += __shfl_xor(rsum[r], 2, 64);
                rsum[r] += __shfl_xor(rsum[r], 4, 64);
                rsum[r] += __shfl_xor(rsum[r], 8, 64);
                lrun[mf][r] = lrun[mf][r] * scl[r] + rsum[r];
            }
#pragma unroll
            for (int dfr = 0; dfr < 4; dfr++)
#pragma unroll
                for (int r = 0; r < 4; r++) outv[mf][dfr][r] *= scl[r];
#pragma unroll
            for (int kvf = 0; kvf < 4; kvf++)
#pragma unroll
                for (int r = 0; r < 4; r++)
                    Pl[(wid * 32 + mf * 16 + lq * 4 + r) * 72 + kvf * 16 + ln15] = (_Float16)sa[kvf][r];
        }
        __syncthreads();

#pragma unroll
        for (int mf = 0; mf < 2; mf++)
#pragma unroll
            for (int kc = 0; kc < 2; kc++){
                f16x8 pa = *(const f16x8*)&Pl[(wid * 32 + mf * 16 + ln15) * 72 + kc * 32 + lq * 8];
#pragma unroll
                for (int dfr = 0; dfr < 4; dfr++){
                    f16x8 vb = *(const f16x8*)&Vt[(dfr * 16 + ln15) * 72 + kc * 32 + lq * 8];
                    outv[mf][dfr] = __builtin_amdgcn_mfma_f32_16x16x32_f16(pa, vb, outv[mf][dfr], 0, 0, 0);
                }
            }
    }

#pragma unroll
    for (int mf = 0; mf < 2; mf++)
#pragma unroll
        for (int dfr = 0; dfr < 4; dfr++)
#pragma unroll
            for (int r = 0; r < 4; r++){
                float val = outv[mf][dfr][r] / lrun[mf][r];
                size_t row = (size_t)(b * SEQ + q0 + wid * 32 + mf * 16 + lq * 4 + r);
                Ob[row * D_MODEL + h * HDIM + dfr * 16 + ln15] = (_Float16)val;
            }
}

// ---------------- LM head: out[b][v] = xf[b] . embed[v] ----------------
__global__ __launch_bounds__(256)
void lmhead_kernel(const float* __restrict__ XF, const float* __restrict__ embed,
                   float* __restrict__ out)
{
    __shared__ float xl[4 * D_MODEL];
    int t = threadIdx.x;
#pragma unroll
    for (int i = 0; i < 8; i++){
        int f = t + i * 256;
        ((float4*)xl)[f] = ((const float4*)XF)[f];
    }
    __syncthreads();
    int lane = t & 63, wid = t >> 6;
    for (int rr = 0; rr < 16; rr++){
        int vrow = blockIdx.x * 64 + wid * 16 + rr;
        const float4* er = (const float4*)(embed + (size_t)vrow * D_MODEL);
        float acc[4] = {0.f, 0.f, 0.f, 0.f};
        for (int j = 0; j < 8; j++){
            float4 e = er[lane + 64 * j];
#pragma unroll
            for (int b = 0; b < 4; b++){
                float4 xv = ((float4*)xl)[b * 512 + lane + 64 * j];
                acc[b] += e.x * xv.x + e.y * xv.y + e.z * xv.z + e.w * xv.w;
            }
        }
#pragma unroll
        for (int b = 0; b < 4; b++)
            for (int off = 32; off; off >>= 1) acc[b] += __shfl_xor(acc[b], off, 64);
        if (lane == 0){
#pragma unroll
            for (int b = 0; b < 4; b++)
                out[(size_t)b * VOCAB + vrow] = acc[b];
        }
    }
}

extern "C" void kernel_launch(void* const* d_in, const int* in_sizes, int n_in,
                              void* d_out, int out_size, void* d_ws, size_t ws_size,
                              hipStream_t stream)
{
    const int*   tok   = (const int*)d_in[0];
    const float* embed = (const float*)d_in[1];
    const float* g_attn = (const float*)d_in[2];
    const float* g_mlp  = (const float*)d_in[3];
    const float* g_fin  = (const float*)d_in[4];
    const int*   wq = (const int*)d_in[5];  const float* sq = (const float*)d_in[6];
    const int*   wk = (const int*)d_in[7];  const float* sk = (const float*)d_in[8];
    const int*   wv = (const int*)d_in[9];  const float* sv = (const float*)d_in[10];
    const int*   wo = (const int*)d_in[11]; const float* so = (const float*)d_in[12];
    const int*   wg = (const int*)d_in[13]; const float* sg = (const float*)d_in[14];
    const int*   wu = (const int*)d_in[15]; const float* su = (const float*)d_in[16];
    const int*   wd = (const int*)d_in[17]; const float* sd = (const float*)d_in[18];
    float* out = (float*)d_out;

    char* p = (char*)d_ws;
    _Float16* Wf = (_Float16*)p;  p += (size_t)60817408 * 2;   // per-layer fp16 weights
    float*    X  = (float*)p;     p += (size_t)NTOK * D_MODEL * 4;
    _Float16* Hb = (_Float16*)p;  p += (size_t)NTOK * D_MODEL * 2;
    _Float16* Qb = (_Float16*)p;  p += (size_t)NTOK * D_MODEL * 2;
    _Float16* Kb = (_Float16*)p;  p += (size_t)NTOK * DKV * 2;
    _Float16* Vb = (_Float16*)p;  p += (size_t)NTOK * DKV * 2;
    _Float16* Ab = (_Float16*)p;  p += (size_t)NTOK * D_MODEL * 2;
    _Float16* Ub = (_Float16*)p;  p += (size_t)NTOK * DFF * 2;
    float*    XF = (float*)p;     p += (size_t)BATCH * D_MODEL * 4;
    float2*   RT = (float2*)p;    p += (size_t)SEQ * 32 * 8;    // rope table

    _Float16* wqf = Wf;                                   // [2048 x 2048]
    _Float16* wkf = wqf + (size_t)D_MODEL * D_MODEL;      // [512 x 2048]
    _Float16* wvf = wkf + (size_t)DKV * D_MODEL;          // [512 x 2048]
    _Float16* wof = wvf + (size_t)DKV * D_MODEL;
    _Float16* wgf = wof + (size_t)D_MODEL * D_MODEL;
    _Float16* wuf = wgf + (size_t)DFF * D_MODEL;
    _Float16* wdf = wuf + (size_t)DFF * D_MODEL;

    gather_kernel<<<NTOK, 256, 0, stream>>>(tok, embed, X);
    rope_table_kernel<<<SEQ * 32 / 256, 256, 0, stream>>>(RT);

    for (int l = 0; l < NLAYER; l++){
        wconv_all_kernel<<<15204352 / 256, 256, 0, stream>>>(
            wq + (size_t)l * D_MODEL * D_MODEL,
            wk + (size_t)l * DKV * D_MODEL,
            wv + (size_t)l * DKV * D_MODEL,
            wo + (size_t)l * D_MODEL * D_MODEL,
            wg + (size_t)l * DFF * D_MODEL,
            wu + (size_t)l * DFF * D_MODEL,
            wd + (size_t)l * D_MODEL * DFF,
            Wf);

        rmsnorm_kernel<<<NTOK, 256, 0, stream>>>(X, g_attn + (size_t)l * D_MODEL, Hb);
        gemm_small<3><<<32 * 12, 512, 0, stream>>>(Hb, wqf,
            sq + (size_t)l * D_MODEL, sk + (size_t)l * DKV, sv + (size_t)l * DKV,
            Qb, Kb, Vb, RT, 32, 12, 3072, D_MODEL);
        attn_kernel<<<1024, 256, 0, stream>>>(Qb, Kb, Vb, Ab);
        gemm_small<1><<<32 * 8, 512, 0, stream>>>(Ab, wof,
            so + (size_t)l * D_MODEL, nullptr, nullptr,
            X, nullptr, nullptr, nullptr, 32, 8, D_MODEL, D_MODEL);

        rmsnorm_kernel<<<NTOK, 256, 0, stream>>>(X, g_mlp + (size_t)l * D_MODEL, Hb);
        gemm_mlp<<<16 * 64, 512, 0, stream>>>(Hb, wuf, wgf,
            su + (size_t)l * DFF, sg + (size_t)l * DFF, Ub, 16, 64, D_MODEL);
        gemm_small<1><<<32 * 8, 512, 0, stream>>>(Ub, wdf,
            sd + (size_t)l * D_MODEL, nullptr, nullptr,
            X, nullptr, nullptr, nullptr, 32, 8, D_MODEL, DFF);
    }

    final_norm_kernel<<<BATCH, 256, 0, stream>>>(X, g_fin, XF);
    lmhead_kernel<<<VOCAB / 64, 256, 0, stream>>>(XF, embed, out);
}

// Round 14
// 3211.497 us; speedup vs baseline: 1.0374x; 1.0374x over previous
//
#include <hip/hip_runtime.h>
#include <hip/hip_bf16.h>

#define D_MODEL 2048
#define NH 32
#define HDIM 64
#define KVHEADS 8
#define DKV 512
#define DFF 8192
#define SEQ 1024
#define BATCH 4
#define NTOK 4096
#define VOCAB 32000
#define NLAYER 4

typedef __attribute__((ext_vector_type(8))) _Float16 f16x8;
typedef __attribute__((ext_vector_type(4))) _Float16 f16x4;
typedef __attribute__((ext_vector_type(4))) float f32x4;
typedef __attribute__((ext_vector_type(4))) int i32x4;

static __device__ __forceinline__ void gload16(const void* g, void* l){
    __builtin_amdgcn_global_load_lds(
        (const __attribute__((address_space(1))) unsigned int*)g,
        (__attribute__((address_space(3))) unsigned int*)l, 16, 0, 0);
}

#define MFMA(d, x, y) d = __builtin_amdgcn_mfma_f32_16x16x32_f16(x, y, d, 0, 0, 0)
#define BAR()    __builtin_amdgcn_s_barrier()
#define LGK0()   do{ asm volatile("s_waitcnt lgkmcnt(0)" ::: "memory"); \
                     __builtin_amdgcn_sched_barrier(0); }while(0)
#define PRIO(x)  __builtin_amdgcn_s_setprio(x)

// ---------------- embedding gather ----------------
__global__ __launch_bounds__(256)
void gather_kernel(const int* __restrict__ tok, const float* __restrict__ embed,
                   float* __restrict__ X)
{
    int row = blockIdx.x;
    int id = tok[row];
    const float4* s = (const float4*)(embed + (size_t)id * D_MODEL);
    float4* d = (float4*)(X + (size_t)row * D_MODEL);
    d[threadIdx.x]       = s[threadIdx.x];
    d[threadIdx.x + 256] = s[threadIdx.x + 256];
}

// ---------------- rope cos/sin table: rt[pos*32+d] = {cos, sin} ----------------
__global__ __launch_bounds__(256)
void rope_table_kernel(float2* __restrict__ rt)
{
    int idx = blockIdx.x * 256 + threadIdx.x;   // 1024*32
    int pos = idx >> 5, d = idx & 31;
    float inv = powf(500000.0f, -(float)d * (1.0f / 32.0f));
    float ang = (float)pos * inv;
    float s, c;
    sincosf(ang, &s, &c);
    rt[idx] = make_float2(c, s);
}

// ---------------- weight convert: all 7 matrices of one layer, 1 dispatch ------
// non-temporal: int32 source never re-read; fp16 dest read much later.
__global__ __launch_bounds__(256)
void wconv_all_kernel(const int* __restrict__ wq, const int* __restrict__ wk,
                      const int* __restrict__ wv, const int* __restrict__ wo,
                      const int* __restrict__ wg, const int* __restrict__ wu,
                      const int* __restrict__ wd, _Float16* __restrict__ O)
{
    int i = blockIdx.x * 256 + threadIdx.x;   // vec index, total 15204352
    const int* s; int loc;
    if      (i <  1048576){ s = wq; loc = i; }
    else if (i <  1310720){ s = wk; loc = i - 1048576; }
    else if (i <  1572864){ s = wv; loc = i - 1310720; }
    else if (i <  2621440){ s = wo; loc = i - 1572864; }
    else if (i <  6815744){ s = wg; loc = i - 2621440; }
    else if (i < 11010048){ s = wu; loc = i - 6815744; }
    else                  { s = wd; loc = i - 11010048; }
    i32x4 w = __builtin_nontemporal_load(&((const i32x4*)s)[loc]);
    f16x4 o;
    o.x = (_Float16)(float)w.x; o.y = (_Float16)(float)w.y;
    o.z = (_Float16)(float)w.z; o.w = (_Float16)(float)w.w;
    __builtin_nontemporal_store(o, &((f16x4*)O)[i]);
}

// ---------------- rmsnorm (fp32 in, fp16 out) ----------------
__global__ __launch_bounds__(256)
void rmsnorm_kernel(const float* __restrict__ X, const float* __restrict__ gamma,
                    _Float16* __restrict__ O)
{
    int row = blockIdx.x;
    const float* x = X + (size_t)row * D_MODEL;
    _Float16* o = O + (size_t)row * D_MODEL;
    int t = threadIdx.x;
    float4 v[2];
    float ss = 0.f;
#pragma unroll
    for (int i = 0; i < 2; i++){
        v[i] = *(const float4*)&x[(t + i*256)*4];
        ss += v[i].x*v[i].x + v[i].y*v[i].y + v[i].z*v[i].z + v[i].w*v[i].w;
    }
    for (int off = 32; off; off >>= 1) ss += __shfl_xor(ss, off, 64);
    __shared__ float red[4];
    __shared__ float invs;
    int lane = t & 63, wid = t >> 6;
    if (lane == 0) red[wid] = ss;
    __syncthreads();
    if (t == 0){
        float s = red[0] + red[1] + red[2] + red[3];
        invs = 1.0f / sqrtf(s / (float)D_MODEL + 1e-5f);
    }
    __syncthreads();
    float inv = invs;
#pragma unroll
    for (int i = 0; i < 2; i++){
        float4 g = *(const float4*)&gamma[(t + i*256)*4];
        f16x4 r;
        r.x = (_Float16)(v[i].x * inv * g.x); r.y = (_Float16)(v[i].y * inv * g.y);
        r.z = (_Float16)(v[i].z * inv * g.z); r.w = (_Float16)(v[i].w * inv * g.w);
        *(f16x4*)&o[(t + i*256)*4] = r;
    }
}

// final norm (fp32 out), last token per batch
__global__ __launch_bounds__(256)
void final_norm_kernel(const float* __restrict__ X, const float* __restrict__ gamma,
                       float* __restrict__ XF)
{
    int b = blockIdx.x;
    const float* x = X + ((size_t)b * SEQ + SEQ - 1) * D_MODEL;
    float* o = XF + (size_t)b * D_MODEL;
    int t = threadIdx.x;
    float4 v[2];
    float ss = 0.f;
#pragma unroll
    for (int i = 0; i < 2; i++){
        v[i] = *(const float4*)&x[(t + i*256)*4];
        ss += v[i].x*v[i].x + v[i].y*v[i].y + v[i].z*v[i].z + v[i].w*v[i].w;
    }
    for (int off = 32; off; off >>= 1) ss += __shfl_xor(ss, off, 64);
    __shared__ float red[4];
    __shared__ float invs;
    int lane = t & 63, wid = t >> 6;
    if (lane == 0) red[wid] = ss;
    __syncthreads();
    if (t == 0){
        float s = red[0] + red[1] + red[2] + red[3];
        invs = 1.0f / sqrtf(s / (float)D_MODEL + 1e-5f);
    }
    __syncthreads();
    float inv = invs;
#pragma unroll
    for (int i = 0; i < 2; i++){
        float4 g = *(const float4*)&gamma[(t + i*256)*4];
        float4 r;
        r.x = v[i].x * inv * g.x; r.y = v[i].y * inv * g.y;
        r.z = v[i].z * inv * g.z; r.w = v[i].w * inv * g.w;
        *(float4*)&o[(t + i*256)*4] = r;
    }
}

// ================= fused MLP GEMM: U = silu(A@Wg^T*sg) * (A@Wu^T*su) =========
// R6/R10 structure: BM=256, BN=128, BK=64, 8 waves (4x2), per-wave 64x64 for
// both U and G.  Balanced phases: 8 ds_read + 16 MFMA per phase, counted
// vmcnt(2) per K-tile.
__global__ __launch_bounds__(512, 2)
void gemm_mlp(const _Float16* __restrict__ A, const _Float16* __restrict__ WU,
              const _Float16* __restrict__ WG,
              const float* __restrict__ su, const float* __restrict__ sg,
              _Float16* __restrict__ U, int MT, int NT, int K)
{
    __shared__ __align__(16) _Float16 AS[2][256 * 64];
    __shared__ __align__(16) _Float16 US[2][128 * 64];
    __shared__ __align__(16) _Float16 GS[3][128 * 64];

    int nwg = MT * NT;
    int flat = blockIdx.x;
    int q = nwg >> 3, r = nwg & 7;
    int xcd = flat & 7, lid = flat >> 3;
    int swz = (xcd < r ? xcd * (q + 1) : r * (q + 1) + (xcd - r) * q) + lid;
    int bm = swz % MT, bn = swz / MT;
    int m0 = bm * 256, n0 = bn * 128;

    const int t = threadIdx.x;
    const int lane = t & 63, wid = t >> 6;
    const int ln15 = lane & 15, lq = lane >> 4;
    const int wm = wid >> 1, wn = wid & 1;   // 4 x 2 wave grid
    const int sw = ln15 & 7;
    const int sl0 = (lq ^ sw) * 8, sl1 = ((4 + lq) ^ sw) * 8;

    const _Float16* srcA[4]; const _Float16* srcU[2]; const _Float16* srcG[2];
#pragma unroll
    for (int rr = 0; rr < 4; rr++){
        int ch = rr * 512 + t;
        int row = ch >> 3, s = (ch & 7) ^ (row & 7);
        srcA[rr] = A + (size_t)(m0 + row) * K + s * 8;
    }
#pragma unroll
    for (int rr = 0; rr < 2; rr++){
        int ch = rr * 512 + t;
        int row = ch >> 3, s = (ch & 7) ^ (row & 7);
        srcU[rr] = WU + (size_t)(n0 + row) * K + s * 8;
        srcG[rr] = WG + (size_t)(n0 + row) * K + s * 8;
    }
#define STG_A4(tile) do{ int _b = (tile) & 1; \
    gload16(srcA[0] + (size_t)(tile)*64, &AS[_b][(wid*64)*8]); \
    gload16(srcA[1] + (size_t)(tile)*64, &AS[_b][(512 + wid*64)*8]); \
    gload16(srcA[2] + (size_t)(tile)*64, &AS[_b][(1024 + wid*64)*8]); \
    gload16(srcA[3] + (size_t)(tile)*64, &AS[_b][(1536 + wid*64)*8]); }while(0)
#define STG_U2(tile) do{ int _b = (tile) & 1; \
    gload16(srcU[0] + (size_t)(tile)*64, &US[_b][(wid*64)*8]); \
    gload16(srcU[1] + (size_t)(tile)*64, &US[_b][(512 + wid*64)*8]); }while(0)
#define STG_G3(tile) do{ int _b = (tile) % 3; \
    gload16(srcG[0] + (size_t)(tile)*64, &GS[_b][(wid*64)*8]); \
    gload16(srcG[1] + (size_t)(tile)*64, &GS[_b][(512 + wid*64)*8]); }while(0)

    f32x4 accU[4][4], accG[4][4];
#pragma unroll
    for (int i = 0; i < 4; i++)
#pragma unroll
        for (int j = 0; j < 4; j++){
            accU[i][j] = (f32x4){0.f, 0.f, 0.f, 0.f};
            accG[i][j] = (f32x4){0.f, 0.f, 0.f, 0.f};
        }

    const int KT = K >> 6;   // 32

    STG_A4(0); STG_U2(0); STG_G3(0); STG_G3(1);
    asm volatile("s_waitcnt vmcnt(2)" ::: "memory");
    BAR();

    for (int kt = 0; kt < KT; ++kt){
        int cur = kt & 1, gcur = kt % 3;
        const _Float16* Ac = AS[cur];
        const _Float16* Uc = US[cur];
        const _Float16* Gc = GS[gcur];
        bool s1 = (kt + 1 < KT), s2 = (kt + 2 < KT);

        // ---- P1: read af k0 + bu k0 (8); stage A(kt+1); MFMA U k0 (16)
        f16x8 afk0[4], afk1[4], buk0[4], buk1[4];
#pragma unroll
        for (int mf = 0; mf < 4; mf++)
            afk0[mf] = *(const f16x8*)&Ac[(wm * 64 + mf * 16 + ln15) * 64 + sl0];
#pragma unroll
        for (int nf = 0; nf < 4; nf++)
            buk0[nf] = *(const f16x8*)&Uc[(wn * 64 + nf * 16 + ln15) * 64 + sl0];
        if (s1) STG_A4(kt + 1);
        BAR(); LGK0(); PRIO(1);
#pragma unroll
        for (int mf = 0; mf < 4; mf++)
#pragma unroll
            for (int nf = 0; nf < 4; nf++)
                MFMA(accU[mf][nf], afk0[mf], buk0[nf]);
        PRIO(0); BAR();

        // ---- P2: read af k1 + bu k1 (8); stage Bu(kt+1); MFMA U k1 (16)
#pragma unroll
        for (int mf = 0; mf < 4; mf++)
            afk1[mf] = *(const f16x8*)&Ac[(wm * 64 + mf * 16 + ln15) * 64 + sl1];
#pragma unroll
        for (int nf = 0; nf < 4; nf++)
            buk1[nf] = *(const f16x8*)&Uc[(wn * 64 + nf * 16 + ln15) * 64 + sl1];
        if (s1) STG_U2(kt + 1);
        BAR(); LGK0(); PRIO(1);
#pragma unroll
        for (int mf = 0; mf < 4; mf++)
#pragma unroll
            for (int nf = 0; nf < 4; nf++)
                MFMA(accU[mf][nf], afk1[mf], buk1[nf]);
        PRIO(0); BAR();

        // ---- P3: read bg k0 + bg k1 (8); stage Bg(kt+2); MFMA G k0 (16)
        f16x8 bgk0[4], bgk1[4];
#pragma unroll
        for (int nf = 0; nf < 4; nf++){
            bgk0[nf] = *(const f16x8*)&Gc[(wn * 64 + nf * 16 + ln15) * 64 + sl0];
            bgk1[nf] = *(const f16x8*)&Gc[(wn * 64 + nf * 16 + ln15) * 64 + sl1];
        }
        if (s2) STG_G3(kt + 2);
        BAR(); LGK0(); PRIO(1);
#pragma unroll
        for (int mf = 0; mf < 4; mf++)
#pragma unroll
            for (int nf = 0; nf < 4; nf++)
                MFMA(accG[mf][nf], afk0[mf], bgk0[nf]);
        PRIO(0); BAR();

        // ---- P4: no reads; MFMA G k1 (16); counted vmcnt
        PRIO(1);
#pragma unroll
        for (int mf = 0; mf < 4; mf++)
#pragma unroll
            for (int nf = 0; nf < 4; nf++)
                MFMA(accG[mf][nf], afk1[mf], bgk1[nf]);
        PRIO(0);
        if (s1){
            if (s2) asm volatile("s_waitcnt vmcnt(2)" ::: "memory");
            else    asm volatile("s_waitcnt vmcnt(0)" ::: "memory");
            BAR();
            __builtin_amdgcn_sched_barrier(0);
        }
    }
#undef STG_A4
#undef STG_U2
#undef STG_G3

#pragma unroll
    for (int mf = 0; mf < 4; mf++){
        int rowb = m0 + wm * 64 + mf * 16 + lq * 4;
#pragma unroll
        for (int nf = 0; nf < 4; nf++){
            int colg = n0 + wn * 64 + nf * 16 + ln15;
            float scu = su[colg], scg = sg[colg];
#pragma unroll
            for (int rr2 = 0; rr2 < 4; rr2++){
                float uv = accU[mf][nf][rr2] * scu;
                float gv = accG[mf][nf][rr2] * scg;
                float sig = 1.0f / (1.0f + expf(-gv));
                U[(size_t)(rowb + rr2) * DFF + colg] = (_Float16)(gv * sig * uv);
            }
        }
    }
}

// ---- gemm_small: BM=128, BN=256, per-wave 64x64, A+B 3-buf (R10 structure) ----
// EPI: 0 = store f16; 1 = fp32 +=; 3 = qkv scatter with fused RoPE (q,k)
template<int EPI>
__global__ __launch_bounds__(512, 2)
void gemm_small(const _Float16* __restrict__ A, const _Float16* __restrict__ W,
                const float* __restrict__ sc0, const float* __restrict__ sc1,
                const float* __restrict__ sc2,
                void* __restrict__ C0, void* __restrict__ C1, void* __restrict__ C2,
                const float2* __restrict__ rt,
                int MT, int NT, int N, int K)
{
    __shared__ __align__(16) _Float16 AS[3][128 * 64];
    __shared__ __align__(16) _Float16 BS[3][256 * 64];

    int nwg = MT * NT;
    int flat = blockIdx.x;
    int q = nwg >> 3, r = nwg & 7;
    int xcd = flat & 7, lid = flat >> 3;
    int swz = (xcd < r ? xcd * (q + 1) : r * (q + 1) + (xcd - r) * q) + lid;
    int bm = swz % MT, bn = swz / MT;
    int m0 = bm * 128, n0 = bn * 256;

    const int t = threadIdx.x;
    const int lane = t & 63, wid = t >> 6;
    const int ln15 = lane & 15, lq = lane >> 4;
    const int wm = wid >> 2, wn = wid & 3;
    const int sw = ln15 & 7;
    const int sl0 = (lq ^ sw) * 8, sl1 = ((4 + lq) ^ sw) * 8;

    const _Float16* srcA[2]; const _Float16* srcB[4];
#pragma unroll
    for (int rr = 0; rr < 2; rr++){
        int ch = rr * 512 + t;
        int row = ch >> 3, s = (ch & 7) ^ (row & 7);
        srcA[rr] = A + (size_t)(m0 + row) * K + s * 8;
    }
#pragma unroll
    for (int rr = 0; rr < 4; rr++){
        int ch = rr * 512 + t;
        int row = ch >> 3, s = (ch & 7) ^ (row & 7);
        srcB[rr] = W + (size_t)(n0 + row) * K + s * 8;
    }
#define STG_A3(tile) do{ int _b = (tile) % 3; \
    gload16(srcA[0] + (size_t)(tile)*64, &AS[_b][(wid*64)*8]); \
    gload16(srcA[1] + (size_t)(tile)*64, &AS[_b][(512 + wid*64)*8]); }while(0)
#define STG_B3(tile) do{ int _b = (tile) % 3; \
    gload16(srcB[0] + (size_t)(tile)*64, &BS[_b][(wid*64)*8]); \
    gload16(srcB[1] + (size_t)(tile)*64, &BS[_b][(512 + wid*64)*8]); \
    gload16(srcB[2] + (size_t)(tile)*64, &BS[_b][(1024 + wid*64)*8]); \
    gload16(srcB[3] + (size_t)(tile)*64, &BS[_b][(1536 + wid*64)*8]); }while(0)

    f32x4 acc[4][4];
#pragma unroll
    for (int i = 0; i < 4; i++)
#pragma unroll
        for (int j = 0; j < 4; j++) acc[i][j] = (f32x4){0.f, 0.f, 0.f, 0.f};

    const int KT = K >> 6;

    STG_A3(0); STG_B3(0); STG_A3(1); STG_B3(1);
    asm volatile("s_waitcnt vmcnt(6)" ::: "memory");
    BAR();

    for (int kt = 0; kt < KT; ++kt){
        int cur = kt % 3;
        const _Float16* Ac = AS[cur];
        const _Float16* Bc = BS[cur];
        bool s1 = (kt + 1 < KT), s2 = (kt + 2 < KT);

        // ---- P1: read af k0 (4) + b k0 (4); stage B(kt+2); MFMA k0 (16)
        f16x8 af0[4], af1[4], bk0[4], bk1[4];
#pragma unroll
        for (int mf = 0; mf < 4; mf++)
            af0[mf] = *(const f16x8*)&Ac[(wm * 64 + mf * 16 + ln15) * 64 + sl0];
#pragma unroll
        for (int nf = 0; nf < 4; nf++)
            bk0[nf] = *(const f16x8*)&Bc[(wn * 64 + nf * 16 + ln15) * 64 + sl0];
        if (s2) STG_B3(kt + 2);
        BAR(); LGK0(); PRIO(1);
#pragma unroll
        for (int mf = 0; mf < 4; mf++)
#pragma unroll
            for (int nf = 0; nf < 4; nf++)
                MFMA(acc[mf][nf], af0[mf], bk0[nf]);
        PRIO(0); BAR();

        // ---- P2: read af k1 (4) + b k1 (4); stage A(kt+2); MFMA k1 (16)
#pragma unroll
        for (int mf = 0; mf < 4; mf++)
            af1[mf] = *(const f16x8*)&Ac[(wm * 64 + mf * 16 + ln15) * 64 + sl1];
#pragma unroll
        for (int nf = 0; nf < 4; nf++)
            bk1[nf] = *(const f16x8*)&Bc[(wn * 64 + nf * 16 + ln15) * 64 + sl1];
        if (s2) STG_A3(kt + 2);
        BAR(); LGK0(); PRIO(1);
#pragma unroll
        for (int mf = 0; mf < 4; mf++)
#pragma unroll
            for (int nf = 0; nf < 4; nf++)
                MFMA(acc[mf][nf], af1[mf], bk1[nf]);
        PRIO(0);
        if (s1){
            if (s2) asm volatile("s_waitcnt vmcnt(6)" ::: "memory");
            else    asm volatile("s_waitcnt vmcnt(0)" ::: "memory");
            BAR();
            __builtin_amdgcn_sched_barrier(0);
        }
    }
#undef STG_A3
#undef STG_B3

    if (EPI == 3){
        const float* sp; _Float16* dp; int nloc, nstr;
        if (n0 < 2048)      { sp = sc0; dp = (_Float16*)C0; nloc = n0;        nstr = 2048; }
        else if (n0 < 2560) { sp = sc1; dp = (_Float16*)C1; nloc = n0 - 2048; nstr = 512; }
        else                { sp = sc2; dp = (_Float16*)C2; nloc = n0 - 2560; nstr = 512; }
        bool dorope = (n0 < 2560);      // q and k get RoPE, v does not
        if (dorope){
#pragma unroll
            for (int mf = 0; mf < 4; mf++){
                int rowb = m0 + wm * 64 + mf * 16 + lq * 4;
#pragma unroll
                for (int nf = 0; nf < 2; nf++){
                    int colg = wn * 64 + nf * 16 + ln15;
                    int d = nf * 16 + ln15;          // 0..31
                    float s1v = sp[nloc + colg], s2v = sp[nloc + colg + 32];
#pragma unroll
                    for (int rr2 = 0; rr2 < 4; rr2++){
                        int row = rowb + rr2;
                        int pos = row & (SEQ - 1);
                        float2 cs = rt[pos * 32 + d];
                        float x1 = acc[mf][nf][rr2] * s1v;
                        float x2 = acc[mf][nf + 2][rr2] * s2v;
                        dp[(size_t)row * nstr + nloc + colg]      = (_Float16)(x1 * cs.x - x2 * cs.y);
                        dp[(size_t)row * nstr + nloc + colg + 32] = (_Float16)(x1 * cs.y + x2 * cs.x);
                    }
                }
            }
        } else {
#pragma unroll
            for (int mf = 0; mf < 4; mf++){
                int rowb = m0 + wm * 64 + mf * 16 + lq * 4;
#pragma unroll
                for (int nf = 0; nf < 4; nf++){
                    int colg = wn * 64 + nf * 16 + ln15;
                    float sc = sp[nloc + colg];
#pragma unroll
                    for (int rr2 = 0; rr2 < 4; rr2++)
                        dp[(size_t)(rowb + rr2) * nstr + nloc + colg] =
                            (_Float16)(acc[mf][nf][rr2] * sc);
                }
            }
        }
    } else {
#pragma unroll
        for (int mf = 0; mf < 4; mf++){
            int rowb = m0 + wm * 64 + mf * 16 + lq * 4;
#pragma unroll
            for (int nf = 0; nf < 4; nf++){
                int colg = n0 + wn * 64 + nf * 16 + ln15;
                float sc = sc0[colg];
#pragma unroll
                for (int rr2 = 0; rr2 < 4; rr2++){
                    size_t idx = (size_t)(rowb + rr2) * N + colg;
                    float val = acc[mf][nf][rr2] * sc;
                    if (EPI == 0){
                        ((_Float16*)C0)[idx] = (_Float16)val;
                    } else {
                        ((float*)C0)[idx] += val;
                    }
                }
            }
        }
    }
}

// ---------------- flash attention (causal, GQA 4:1, fp16) ----------------
// T14 async-split + CU-load-balanced qt decode.
__global__ __launch_bounds__(256)
void attn_kernel(const _Float16* __restrict__ Qb, const _Float16* __restrict__ Kb,
                 const _Float16* __restrict__ Vb, _Float16* __restrict__ Ob)
{
    int bid = blockIdx.x;
    int qt = bid >> 7, h = bid & 31, b = (bid >> 5) & 3;
    int kvh = h >> 2;
    int q0 = qt * 128;
    int t = threadIdx.x, lane = t & 63, wid = t >> 6;
    int ln15 = lane & 15, lq = lane >> 4;

    __shared__ __align__(16) _Float16 Ksm[64 * 72];
    __shared__ __align__(16) _Float16 Vt[64 * 72];
    __shared__ __align__(16) _Float16 Pl[128 * 72];

    f16x8 qf[2][2];
    int qrow_g = b * SEQ + q0 + wid * 32;
#pragma unroll
    for (int mf = 0; mf < 2; mf++)
#pragma unroll
        for (int dc = 0; dc < 2; dc++)
            qf[mf][dc] = *(const f16x8*)(Qb + (size_t)(qrow_g + mf * 16 + ln15) * D_MODEL
                                         + h * HDIM + dc * 32 + lq * 8);

    f32x4 outv[2][4];
#pragma unroll
    for (int i = 0; i < 2; i++)
#pragma unroll
        for (int j = 0; j < 4; j++) outv[i][j] = (f32x4){0.f, 0.f, 0.f, 0.f};
    float mrun[2][4], lrun[2][4];
#pragma unroll
    for (int i = 0; i < 2; i++)
#pragma unroll
        for (int r = 0; r < 4; r++){ mrun[i][r] = -1e30f; lrun[i][r] = 0.f; }

    int ntile = (q0 + 128) >> 6;
    int ld_row = (t + 0) >> 3, ld_c8 = t & 7;
    int ld_row1 = (t + 256) >> 3;

    f16x8 k8[2], v8[2];
    {
        size_t base0 = (size_t)(b * SEQ + ld_row) * DKV + kvh * HDIM + ld_c8 * 8;
        size_t base1 = (size_t)(b * SEQ + ld_row1) * DKV + kvh * HDIM + ld_c8 * 8;
        k8[0] = *(const f16x8*)&Kb[base0];  v8[0] = *(const f16x8*)&Vb[base0];
        k8[1] = *(const f16x8*)&Kb[base1];  v8[1] = *(const f16x8*)&Vb[base1];
    }

    for (int kt = 0; kt < ntile; kt++){
        __syncthreads();
#pragma unroll
        for (int i = 0; i < 2; i++){
            int row = (i == 0) ? ld_row : ld_row1;
            *(f16x8*)&Ksm[row * 72 + ld_c8 * 8] = k8[i];
#pragma unroll
            for (int j = 0; j < 8; j++)
                Vt[(ld_c8 * 8 + j) * 72 + row] = v8[i][j];
        }
        __syncthreads();

        if (kt + 1 < ntile){
            size_t base0 = (size_t)(b * SEQ + (kt + 1) * 64 + ld_row) * DKV + kvh * HDIM + ld_c8 * 8;
            size_t base1 = (size_t)(b * SEQ + (kt + 1) * 64 + ld_row1) * DKV + kvh * HDIM + ld_c8 * 8;
            k8[0] = *(const f16x8*)&Kb[base0];  v8[0] = *(const f16x8*)&Vb[base0];
            k8[1] = *(const f16x8*)&Kb[base1];  v8[1] = *(const f16x8*)&Vb[base1];
        }

#pragma unroll
        for (int mf = 0; mf < 2; mf++){
            f32x4 sa[4];
#pragma unroll
            for (int kvf = 0; kvf < 4; kvf++) sa[kvf] = (f32x4){0.f, 0.f, 0.f, 0.f};
#pragma unroll
            for (int kvf = 0; kvf < 4; kvf++)
#pragma unroll
                for (int dc = 0; dc < 2; dc++){
                    f16x8 kb = *(const f16x8*)&Ksm[(kvf * 16 + ln15) * 72 + dc * 32 + lq * 8];
                    sa[kvf] = __builtin_amdgcn_mfma_f32_16x16x32_f16(qf[mf][dc], kb, sa[kvf], 0, 0, 0);
                }
            int qbase = q0 + wid * 32 + mf * 16 + lq * 4;
            float rowmax[4] = {-1e30f, -1e30f, -1e30f, -1e30f};
#pragma unroll
            for (int kvf = 0; kvf < 4; kvf++){
                int kva = kt * 64 + kvf * 16 + ln15;
#pragma unroll
                for (int r = 0; r < 4; r++){
                    float sv = sa[kvf][r] * 0.125f;
                    if (kva > qbase + r) sv = -1e9f;
                    sa[kvf][r] = sv;
                    rowmax[r] = fmaxf(rowmax[r], sv);
                }
            }
#pragma unroll
            for (int r = 0; r < 4; r++){
                rowmax[r] = fmaxf(rowmax[r], __shfl_xor(rowmax[r], 1, 64));
                rowmax[r] = fmaxf(rowmax[r], __shfl_xor(rowmax[r], 2, 64));
                rowmax[r] = fmaxf(rowmax[r], __shfl_xor(rowmax[r], 4, 64));
                rowmax[r] = fmaxf(rowmax[r], __shfl_xor(rowmax[r], 8, 64));
            }
            float scl[4], rsum[4];
#pragma unroll
            for (int r = 0; r < 4; r++){
                float mo = mrun[mf][r];
                float mn = fmaxf(mo, rowmax[r]);
                scl[r] = expf(mo - mn);
                mrun[mf][r] = mn;
                rsum[r] = 0.f;
            }
#pragma unroll
            for (int kvf = 0; kvf < 4; kvf++)
#pragma unroll
                for (int r = 0; r < 4; r++){
                    float p = expf(sa[kvf][r] - mrun[mf][r]);
                    sa[kvf][r] = p;
                    rsum[r] += p;
                }
#pragma unroll
            for (int r = 0; r < 4; r++){
                rsum[r] += __shfl_xor(rsum[r], 1, 64);
                rsum[r] += __shfl_xor(rsum[r], 2, 64);
                rsum[r] += __shfl_xor(rsum[r], 4, 64);
                rsum[r] += __shfl_xor(rsum[r], 8, 64);
                lrun[mf][r] = lrun[mf][r] * scl[r] + rsum[r];
            }
#pragma unroll
            for (int dfr = 0; dfr < 4; dfr++)
#pragma unroll
                for (int r = 0; r < 4; r++) outv[mf][dfr][r] *= scl[r];
#pragma unroll
            for (int kvf = 0; kvf < 4; kvf++)
#pragma unroll
                for (int r = 0; r < 4; r++)
                    Pl[(wid * 32 + mf * 16 + lq * 4 + r) * 72 + kvf * 16 + ln15] = (_Float16)sa[kvf][r];
        }
        __syncthreads();

#pragma unroll
        for (int mf = 0; mf < 2; mf++)
#pragma unroll
            for (int kc = 0; kc < 2; kc++){
                f16x8 pa = *(const f16x8*)&Pl[(wid * 32 + mf * 16 + ln15) * 72 + kc * 32 + lq * 8];
#pragma unroll
                for (int dfr = 0; dfr < 4; dfr++){
                    f16x8 vb = *(const f16x8*)&Vt[(dfr * 16 + ln15) * 72 + kc * 32 + lq * 8];
                    outv[mf][dfr] = __builtin_amdgcn_mfma_f32_16x16x32_f16(pa, vb, outv[mf][dfr], 0, 0, 0);
                }
            }
    }

#pragma unroll
    for (int mf = 0; mf < 2; mf++)
#pragma unroll
        for (int dfr = 0; dfr < 4; dfr++)
#pragma unroll
            for (int r = 0; r < 4; r++){
                float val = outv[mf][dfr][r] / lrun[mf][r];
                size_t row = (size_t)(b * SEQ + q0 + wid * 32 + mf * 16 + lq * 4 + r);
                Ob[row * D_MODEL + h * HDIM + dfr * 16 + ln15] = (_Float16)val;
            }
}

// ---------------- LM head: out[b][v] = xf[b] . embed[v] ----------------
__global__ __launch_bounds__(256)
void lmhead_kernel(const float* __restrict__ XF, const float* __restrict__ embed,
                   float* __restrict__ out)
{
    __shared__ float xl[4 * D_MODEL];
    int t = threadIdx.x;
#pragma unroll
    for (int i = 0; i < 8; i++){
        int f = t + i * 256;
        ((float4*)xl)[f] = ((const float4*)XF)[f];
    }
    __syncthreads();
    int lane = t & 63, wid = t >> 6;
    for (int rr = 0; rr < 16; rr++){
        int vrow = blockIdx.x * 64 + wid * 16 + rr;
        const float4* er = (const float4*)(embed + (size_t)vrow * D_MODEL);
        float acc[4] = {0.f, 0.f, 0.f, 0.f};
        for (int j = 0; j < 8; j++){
            float4 e = er[lane + 64 * j];
#pragma unroll
            for (int b = 0; b < 4; b++){
                float4 xv = ((float4*)xl)[b * 512 + lane + 64 * j];
                acc[b] += e.x * xv.x + e.y * xv.y + e.z * xv.z + e.w * xv.w;
            }
        }
#pragma unroll
        for (int b = 0; b < 4; b++)
            for (int off = 32; off; off >>= 1) acc[b] += __shfl_xor(acc[b], off, 64);
        if (lane == 0){
#pragma unroll
            for (int b = 0; b < 4; b++)
                out[(size_t)b * VOCAB + vrow] = acc[b];
        }
    }
}

extern "C" void kernel_launch(void* const* d_in, const int* in_sizes, int n_in,
                              void* d_out, int out_size, void* d_ws, size_t ws_size,
                              hipStream_t stream)
{
    const int*   tok   = (const int*)d_in[0];
    const float* embed = (const float*)d_in[1];
    const float* g_attn = (const float*)d_in[2];
    const float* g_mlp  = (const float*)d_in[3];
    const float* g_fin  = (const float*)d_in[4];
    const int*   wq = (const int*)d_in[5];  const float* sq = (const float*)d_in[6];
    const int*   wk = (const int*)d_in[7];  const float* sk = (const float*)d_in[8];
    const int*   wv = (const int*)d_in[9];  const float* sv = (const float*)d_in[10];
    const int*   wo = (const int*)d_in[11]; const float* so = (const float*)d_in[12];
    const int*   wg = (const int*)d_in[13]; const float* sg = (const float*)d_in[14];
    const int*   wu = (const int*)d_in[15]; const float* su = (const float*)d_in[16];
    const int*   wd = (const int*)d_in[17]; const float* sd = (const float*)d_in[18];
    float* out = (float*)d_out;

    char* p = (char*)d_ws;
    _Float16* Wf = (_Float16*)p;  p += (size_t)60817408 * 2;   // per-layer fp16 weights
    float*    X  = (float*)p;     p += (size_t)NTOK * D_MODEL * 4;
    _Float16* Hb = (_Float16*)p;  p += (size_t)NTOK * D_MODEL * 2;
    _Float16* Qb = (_Float16*)p;  p += (size_t)NTOK * D_MODEL * 2;
    _Float16* Kb = (_Float16*)p;  p += (size_t)NTOK * DKV * 2;
    _Float16* Vb = (_Float16*)p;  p += (size_t)NTOK * DKV * 2;
    _Float16* Ab = (_Float16*)p;  p += (size_t)NTOK * D_MODEL * 2;
    _Float16* Ub = (_Float16*)p;  p += (size_t)NTOK * DFF * 2;
    float*    XF = (float*)p;     p += (size_t)BATCH * D_MODEL * 4;
    float2*   RT = (float2*)p;    p += (size_t)SEQ * 32 * 8;    // rope table

    _Float16* wqf = Wf;                                   // [2048 x 2048]
    _Float16* wkf = wqf + (size_t)D_MODEL * D_MODEL;      // [512 x 2048]
    _Float16* wvf = wkf + (size_t)DKV * D_MODEL;          // [512 x 2048]
    _Float16* wof = wvf + (size_t)DKV * D_MODEL;
    _Float16* wgf = wof + (size_t)D_MODEL * D_MODEL;
    _Float16* wuf = wgf + (size_t)DFF * D_MODEL;
    _Float16* wdf = wuf + (size_t)DFF * D_MODEL;

    gather_kernel<<<NTOK, 256, 0, stream>>>(tok, embed, X);
    rope_table_kernel<<<SEQ * 32 / 256, 256, 0, stream>>>(RT);

    for (int l = 0; l < NLAYER; l++){
        wconv_all_kernel<<<15204352 / 256, 256, 0, stream>>>(
            wq + (size_t)l * D_MODEL * D_MODEL,
            wk + (size_t)l * DKV * D_MODEL,
            wv + (size_t)l * DKV * D_MODEL,
            wo + (size_t)l * D_MODEL * D_MODEL,
            wg + (size_t)l * DFF * D_MODEL,
            wu + (size_t)l * DFF * D_MODEL,
            wd + (size_t)l * D_MODEL * DFF,
            Wf);

        rmsnorm_kernel<<<NTOK, 256, 0, stream>>>(X, g_attn + (size_t)l * D_MODEL, Hb);
        gemm_small<3><<<32 * 12, 512, 0, stream>>>(Hb, wqf,
            sq + (size_t)l * D_MODEL, sk + (size_t)l * DKV, sv + (size_t)l * DKV,
            Qb, Kb, Vb, RT, 32, 12, 3072, D_MODEL);
        attn_kernel<<<1024, 256, 0, stream>>>(Qb, Kb, Vb, Ab);
        gemm_small<1><<<32 * 8, 512, 0, stream>>>(Ab, wof,
            so + (size_t)l * D_MODEL, nullptr, nullptr,
            X, nullptr, nullptr, nullptr, 32, 8, D_MODEL, D_MODEL);

        rmsnorm_kernel<<<NTOK, 256, 0, stream>>>(X, g_mlp + (size_t)l * D_MODEL, Hb);
        gemm_mlp<<<16 * 64, 512, 0, stream>>>(Hb, wuf, wgf,
            su + (size_t)l * DFF, sg + (size_t)l * DFF, Ub, 16, 64, D_MODEL);
        gemm_small<1><<<32 * 8, 512, 0, stream>>>(Ub, wdf,
            sd + (size_t)l * D_MODEL, nullptr, nullptr,
            X, nullptr, nullptr, nullptr, 32, 8, D_MODEL, DFF);
    }

    final_norm_kernel<<<BATCH, 256, 0, stream>>>(X, g_fin, XF);
    lmhead_kernel<<<VOCAB / 64, 256, 0, stream>>>(XF, embed, out);
}

// Round 15
// 3098.771 us; speedup vs baseline: 1.0752x; 1.0364x over previous
//
#include <hip/hip_runtime.h>
#include <hip/hip_bf16.h>

#define D_MODEL 2048
#define NH 32
#define HDIM 64
#define KVHEADS 8
#define DKV 512
#define DFF 8192
#define SEQ 1024
#define BATCH 4
#define NTOK 4096
#define VOCAB 32000
#define NLAYER 4

typedef __attribute__((ext_vector_type(8))) _Float16 f16x8;
typedef __attribute__((ext_vector_type(4))) _Float16 f16x4;
typedef __attribute__((ext_vector_type(4))) float f32x4;
typedef __attribute__((ext_vector_type(4))) int i32x4;

static __device__ __forceinline__ void gload16(const void* g, void* l){
    __builtin_amdgcn_global_load_lds(
        (const __attribute__((address_space(1))) unsigned int*)g,
        (__attribute__((address_space(3))) unsigned int*)l, 16, 0, 0);
}

#define MFMA(d, x, y) d = __builtin_amdgcn_mfma_f32_16x16x32_f16(x, y, d, 0, 0, 0)
#define BAR()    __builtin_amdgcn_s_barrier()
#define LGK0()   do{ asm volatile("s_waitcnt lgkmcnt(0)" ::: "memory"); \
                     __builtin_amdgcn_sched_barrier(0); }while(0)
#define PRIO(x)  __builtin_amdgcn_s_setprio(x)

// ---------------- embedding gather ----------------
__global__ __launch_bounds__(256)
void gather_kernel(const int* __restrict__ tok, const float* __restrict__ embed,
                   float* __restrict__ X)
{
    int row = blockIdx.x;
    int id = tok[row];
    const float4* s = (const float4*)(embed + (size_t)id * D_MODEL);
    float4* d = (float4*)(X + (size_t)row * D_MODEL);
    d[threadIdx.x]       = s[threadIdx.x];
    d[threadIdx.x + 256] = s[threadIdx.x + 256];
}

// ---------------- rope cos/sin table: rt[pos*32+d] = {cos, sin} ----------------
__global__ __launch_bounds__(256)
void rope_table_kernel(float2* __restrict__ rt)
{
    int idx = blockIdx.x * 256 + threadIdx.x;   // 1024*32
    int pos = idx >> 5, d = idx & 31;
    float inv = powf(500000.0f, -(float)d * (1.0f / 32.0f));
    float ang = (float)pos * inv;
    float s, c;
    sincosf(ang, &s, &c);
    rt[idx] = make_float2(c, s);
}

// ---------------- weight convert: all 7 matrices of one layer, 1 dispatch ------
__global__ __launch_bounds__(256)
void wconv_all_kernel(const int* __restrict__ wq, const int* __restrict__ wk,
                      const int* __restrict__ wv, const int* __restrict__ wo,
                      const int* __restrict__ wg, const int* __restrict__ wu,
                      const int* __restrict__ wd, _Float16* __restrict__ O)
{
    int i = blockIdx.x * 256 + threadIdx.x;   // vec index, total 15204352
    const int* s; int loc;
    if      (i <  1048576){ s = wq; loc = i; }
    else if (i <  1310720){ s = wk; loc = i - 1048576; }
    else if (i <  1572864){ s = wv; loc = i - 1310720; }
    else if (i <  2621440){ s = wo; loc = i - 1572864; }
    else if (i <  6815744){ s = wg; loc = i - 2621440; }
    else if (i < 11010048){ s = wu; loc = i - 6815744; }
    else                  { s = wd; loc = i - 11010048; }
    i32x4 w = __builtin_nontemporal_load(&((const i32x4*)s)[loc]);
    f16x4 o;
    o.x = (_Float16)(float)w.x; o.y = (_Float16)(float)w.y;
    o.z = (_Float16)(float)w.z; o.w = (_Float16)(float)w.w;
    __builtin_nontemporal_store(o, &((f16x4*)O)[i]);
}

// ---------------- rmsnorm (fp32 in, fp16 out) ----------------
__global__ __launch_bounds__(256)
void rmsnorm_kernel(const float* __restrict__ X, const float* __restrict__ gamma,
                    _Float16* __restrict__ O)
{
    int row = blockIdx.x;
    const float* x = X + (size_t)row * D_MODEL;
    _Float16* o = O + (size_t)row * D_MODEL;
    int t = threadIdx.x;
    float4 v[2];
    float ss = 0.f;
#pragma unroll
    for (int i = 0; i < 2; i++){
        v[i] = *(const float4*)&x[(t + i*256)*4];
        ss += v[i].x*v[i].x + v[i].y*v[i].y + v[i].z*v[i].z + v[i].w*v[i].w;
    }
    for (int off = 32; off; off >>= 1) ss += __shfl_xor(ss, off, 64);
    __shared__ float red[4];
    __shared__ float invs;
    int lane = t & 63, wid = t >> 6;
    if (lane == 0) red[wid] = ss;
    __syncthreads();
    if (t == 0){
        float s = red[0] + red[1] + red[2] + red[3];
        invs = 1.0f / sqrtf(s / (float)D_MODEL + 1e-5f);
    }
    __syncthreads();
    float inv = invs;
#pragma unroll
    for (int i = 0; i < 2; i++){
        float4 g = *(const float4*)&gamma[(t + i*256)*4];
        f16x4 r;
        r.x = (_Float16)(v[i].x * inv * g.x); r.y = (_Float16)(v[i].y * inv * g.y);
        r.z = (_Float16)(v[i].z * inv * g.z); r.w = (_Float16)(v[i].w * inv * g.w);
        *(f16x4*)&o[(t + i*256)*4] = r;
    }
}

// final norm (fp32 out), last token per batch
__global__ __launch_bounds__(256)
void final_norm_kernel(const float* __restrict__ X, const float* __restrict__ gamma,
                       float* __restrict__ XF)
{
    int b = blockIdx.x;
    const float* x = X + ((size_t)b * SEQ + SEQ - 1) * D_MODEL;
    float* o = XF + (size_t)b * D_MODEL;
    int t = threadIdx.x;
    float4 v[2];
    float ss = 0.f;
#pragma unroll
    for (int i = 0; i < 2; i++){
        v[i] = *(const float4*)&x[(t + i*256)*4];
        ss += v[i].x*v[i].x + v[i].y*v[i].y + v[i].z*v[i].z + v[i].w*v[i].w;
    }
    for (int off = 32; off; off >>= 1) ss += __shfl_xor(ss, off, 64);
    __shared__ float red[4];
    __shared__ float invs;
    int lane = t & 63, wid = t >> 6;
    if (lane == 0) red[wid] = ss;
    __syncthreads();
    if (t == 0){
        float s = red[0] + red[1] + red[2] + red[3];
        invs = 1.0f / sqrtf(s / (float)D_MODEL + 1e-5f);
    }
    __syncthreads();
    float inv = invs;
#pragma unroll
    for (int i = 0; i < 2; i++){
        float4 g = *(const float4*)&gamma[(t + i*256)*4];
        float4 r;
        r.x = v[i].x * inv * g.x; r.y = v[i].y * inv * g.y;
        r.z = v[i].z * inv * g.z; r.w = v[i].w * inv * g.w;
        *(float4*)&o[(t + i*256)*4] = r;
    }
}

// ========== dual-panel GEMM core (R6/R10-proven schedule) ==========
// Computes accU (cols n0..n0+127 via WU) and accG (cols +128.. via WG) for
// A[256 x K].  4 balanced phases/K-tile, counted vmcnt(2).
// EPI 0: U = silu(g)*u fused MLP store.  EPI 1: atomicAdd both halves to fp32 C.

// ================= fused MLP GEMM: U = silu(A@Wg^T*sg) * (A@Wu^T*su) =========
__global__ __launch_bounds__(512, 2)
void gemm_mlp(const _Float16* __restrict__ A, const _Float16* __restrict__ WU,
              const _Float16* __restrict__ WG,
              const float* __restrict__ su, const float* __restrict__ sg,
              _Float16* __restrict__ U, int MT, int NT, int K)
{
    __shared__ __align__(16) _Float16 AS[2][256 * 64];
    __shared__ __align__(16) _Float16 US[2][128 * 64];
    __shared__ __align__(16) _Float16 GS[3][128 * 64];

    int nwg = MT * NT;
    int flat = blockIdx.x;
    int q = nwg >> 3, r = nwg & 7;
    int xcd = flat & 7, lid = flat >> 3;
    int swz = (xcd < r ? xcd * (q + 1) : r * (q + 1) + (xcd - r) * q) + lid;
    int bm = swz % MT, bn = swz / MT;
    int m0 = bm * 256, n0 = bn * 128;

    const int t = threadIdx.x;
    const int lane = t & 63, wid = t >> 6;
    const int ln15 = lane & 15, lq = lane >> 4;
    const int wm = wid >> 1, wn = wid & 1;   // 4 x 2 wave grid
    const int sw = ln15 & 7;
    const int sl0 = (lq ^ sw) * 8, sl1 = ((4 + lq) ^ sw) * 8;

    const _Float16* srcA[4]; const _Float16* srcU[2]; const _Float16* srcG[2];
#pragma unroll
    for (int rr = 0; rr < 4; rr++){
        int ch = rr * 512 + t;
        int row = ch >> 3, s = (ch & 7) ^ (row & 7);
        srcA[rr] = A + (size_t)(m0 + row) * K + s * 8;
    }
#pragma unroll
    for (int rr = 0; rr < 2; rr++){
        int ch = rr * 512 + t;
        int row = ch >> 3, s = (ch & 7) ^ (row & 7);
        srcU[rr] = WU + (size_t)(n0 + row) * K + s * 8;
        srcG[rr] = WG + (size_t)(n0 + row) * K + s * 8;
    }
#define STG_A4(tile) do{ int _b = (tile) & 1; \
    gload16(srcA[0] + (size_t)(tile)*64, &AS[_b][(wid*64)*8]); \
    gload16(srcA[1] + (size_t)(tile)*64, &AS[_b][(512 + wid*64)*8]); \
    gload16(srcA[2] + (size_t)(tile)*64, &AS[_b][(1024 + wid*64)*8]); \
    gload16(srcA[3] + (size_t)(tile)*64, &AS[_b][(1536 + wid*64)*8]); }while(0)
#define STG_U2(tile) do{ int _b = (tile) & 1; \
    gload16(srcU[0] + (size_t)(tile)*64, &US[_b][(wid*64)*8]); \
    gload16(srcU[1] + (size_t)(tile)*64, &US[_b][(512 + wid*64)*8]); }while(0)
#define STG_G3(tile) do{ int _b = (tile) % 3; \
    gload16(srcG[0] + (size_t)(tile)*64, &GS[_b][(wid*64)*8]); \
    gload16(srcG[1] + (size_t)(tile)*64, &GS[_b][(512 + wid*64)*8]); }while(0)

    f32x4 accU[4][4], accG[4][4];
#pragma unroll
    for (int i = 0; i < 4; i++)
#pragma unroll
        for (int j = 0; j < 4; j++){
            accU[i][j] = (f32x4){0.f, 0.f, 0.f, 0.f};
            accG[i][j] = (f32x4){0.f, 0.f, 0.f, 0.f};
        }

    const int KT = K >> 6;

    STG_A4(0); STG_U2(0); STG_G3(0); STG_G3(1);
    asm volatile("s_waitcnt vmcnt(2)" ::: "memory");
    BAR();

    for (int kt = 0; kt < KT; ++kt){
        int cur = kt & 1, gcur = kt % 3;
        const _Float16* Ac = AS[cur];
        const _Float16* Uc = US[cur];
        const _Float16* Gc = GS[gcur];
        bool s1 = (kt + 1 < KT), s2 = (kt + 2 < KT);

        f16x8 afk0[4], afk1[4], buk0[4], buk1[4];
#pragma unroll
        for (int mf = 0; mf < 4; mf++)
            afk0[mf] = *(const f16x8*)&Ac[(wm * 64 + mf * 16 + ln15) * 64 + sl0];
#pragma unroll
        for (int nf = 0; nf < 4; nf++)
            buk0[nf] = *(const f16x8*)&Uc[(wn * 64 + nf * 16 + ln15) * 64 + sl0];
        if (s1) STG_A4(kt + 1);
        BAR(); LGK0(); PRIO(1);
#pragma unroll
        for (int mf = 0; mf < 4; mf++)
#pragma unroll
            for (int nf = 0; nf < 4; nf++)
                MFMA(accU[mf][nf], afk0[mf], buk0[nf]);
        PRIO(0); BAR();

#pragma unroll
        for (int mf = 0; mf < 4; mf++)
            afk1[mf] = *(const f16x8*)&Ac[(wm * 64 + mf * 16 + ln15) * 64 + sl1];
#pragma unroll
        for (int nf = 0; nf < 4; nf++)
            buk1[nf] = *(const f16x8*)&Uc[(wn * 64 + nf * 16 + ln15) * 64 + sl1];
        if (s1) STG_U2(kt + 1);
        BAR(); LGK0(); PRIO(1);
#pragma unroll
        for (int mf = 0; mf < 4; mf++)
#pragma unroll
            for (int nf = 0; nf < 4; nf++)
                MFMA(accU[mf][nf], afk1[mf], buk1[nf]);
        PRIO(0); BAR();

        f16x8 bgk0[4], bgk1[4];
#pragma unroll
        for (int nf = 0; nf < 4; nf++){
            bgk0[nf] = *(const f16x8*)&Gc[(wn * 64 + nf * 16 + ln15) * 64 + sl0];
            bgk1[nf] = *(const f16x8*)&Gc[(wn * 64 + nf * 16 + ln15) * 64 + sl1];
        }
        if (s2) STG_G3(kt + 2);
        BAR(); LGK0(); PRIO(1);
#pragma unroll
        for (int mf = 0; mf < 4; mf++)
#pragma unroll
            for (int nf = 0; nf < 4; nf++)
                MFMA(accG[mf][nf], afk0[mf], bgk0[nf]);
        PRIO(0); BAR();

        PRIO(1);
#pragma unroll
        for (int mf = 0; mf < 4; mf++)
#pragma unroll
            for (int nf = 0; nf < 4; nf++)
                MFMA(accG[mf][nf], afk1[mf], bgk1[nf]);
        PRIO(0);
        if (s1){
            if (s2) asm volatile("s_waitcnt vmcnt(2)" ::: "memory");
            else    asm volatile("s_waitcnt vmcnt(0)" ::: "memory");
            BAR();
            __builtin_amdgcn_sched_barrier(0);
        }
    }
#undef STG_A4
#undef STG_U2
#undef STG_G3

#pragma unroll
    for (int mf = 0; mf < 4; mf++){
        int rowb = m0 + wm * 64 + mf * 16 + lq * 4;
#pragma unroll
        for (int nf = 0; nf < 4; nf++){
            int colg = n0 + wn * 64 + nf * 16 + ln15;
            float scu = su[colg], scg = sg[colg];
#pragma unroll
            for (int rr2 = 0; rr2 < 4; rr2++){
                float uv = accU[mf][nf][rr2] * scu;
                float gv = accG[mf][nf][rr2] * scg;
                float sig = 1.0f / (1.0f + expf(-gv));
                U[(size_t)(rowb + rr2) * DFF + colg] = (_Float16)(gv * sig * uv);
            }
        }
    }
}

// ================= gemm_wd: split-K dual-panel, atomicAdd epilogue ==========
// C[M x 256-col block] += A[M,K] @ W^T * scale, K split 2-way across blocks.
// Same pipeline as gemm_mlp; "U" = cols n0..+127, "G" = cols n0+128..+255.
__global__ __launch_bounds__(512, 2)
void gemm_wd(const _Float16* __restrict__ Afull, const _Float16* __restrict__ Wfull,
             const float* __restrict__ sc, float* __restrict__ C,
             int MT, int NT, int N, int Kfull)
{
    __shared__ __align__(16) _Float16 AS[2][256 * 64];
    __shared__ __align__(16) _Float16 US[2][128 * 64];
    __shared__ __align__(16) _Float16 GS[3][128 * 64];

    int flat = blockIdx.x;
    int kz = flat & 1;                 // split-K half
    int rest = flat >> 1;
    int nwg = MT * NT;
    int q = nwg >> 3, r = nwg & 7;
    int xcd = rest & 7, lid = rest >> 3;
    int swz = (xcd < r ? xcd * (q + 1) : r * (q + 1) + (xcd - r) * q) + lid;
    int bm = swz % MT, bn = swz / MT;
    int m0 = bm * 256, n0 = bn * 256;
    const int K = Kfull >> 1;          // this block's K range
    const _Float16* A = Afull + (size_t)kz * K;
    const _Float16* W = Wfull + (size_t)kz * K;

    const int t = threadIdx.x;
    const int lane = t & 63, wid = t >> 6;
    const int ln15 = lane & 15, lq = lane >> 4;
    const int wm = wid >> 1, wn = wid & 1;
    const int sw = ln15 & 7;
    const int sl0 = (lq ^ sw) * 8, sl1 = ((4 + lq) ^ sw) * 8;

    const _Float16* srcA[4]; const _Float16* srcU[2]; const _Float16* srcG[2];
#pragma unroll
    for (int rr = 0; rr < 4; rr++){
        int ch = rr * 512 + t;
        int row = ch >> 3, s = (ch & 7) ^ (row & 7);
        srcA[rr] = A + (size_t)(m0 + row) * Kfull + s * 8;
    }
#pragma unroll
    for (int rr = 0; rr < 2; rr++){
        int ch = rr * 512 + t;
        int row = ch >> 3, s = (ch & 7) ^ (row & 7);
        srcU[rr] = W + (size_t)(n0 + row) * Kfull + s * 8;
        srcG[rr] = W + (size_t)(n0 + 128 + row) * Kfull + s * 8;
    }
#define STG_A4(tile) do{ int _b = (tile) & 1; \
    gload16(srcA[0] + (size_t)(tile)*64, &AS[_b][(wid*64)*8]); \
    gload16(srcA[1] + (size_t)(tile)*64, &AS[_b][(512 + wid*64)*8]); \
    gload16(srcA[2] + (size_t)(tile)*64, &AS[_b][(1024 + wid*64)*8]); \
    gload16(srcA[3] + (size_t)(tile)*64, &AS[_b][(1536 + wid*64)*8]); }while(0)
#define STG_U2(tile) do{ int _b = (tile) & 1; \
    gload16(srcU[0] + (size_t)(tile)*64, &US[_b][(wid*64)*8]); \
    gload16(srcU[1] + (size_t)(tile)*64, &US[_b][(512 + wid*64)*8]); }while(0)
#define STG_G3(tile) do{ int _b = (tile) % 3; \
    gload16(srcG[0] + (size_t)(tile)*64, &GS[_b][(wid*64)*8]); \
    gload16(srcG[1] + (size_t)(tile)*64, &GS[_b][(512 + wid*64)*8]); }while(0)

    f32x4 accU[4][4], accG[4][4];
#pragma unroll
    for (int i = 0; i < 4; i++)
#pragma unroll
        for (int j = 0; j < 4; j++){
            accU[i][j] = (f32x4){0.f, 0.f, 0.f, 0.f};
            accG[i][j] = (f32x4){0.f, 0.f, 0.f, 0.f};
        }

    const int KT = K >> 6;

    STG_A4(0); STG_U2(0); STG_G3(0); STG_G3(1);
    asm volatile("s_waitcnt vmcnt(2)" ::: "memory");
    BAR();

    for (int kt = 0; kt < KT; ++kt){
        int cur = kt & 1, gcur = kt % 3;
        const _Float16* Ac = AS[cur];
        const _Float16* Uc = US[cur];
        const _Float16* Gc = GS[gcur];
        bool s1 = (kt + 1 < KT), s2 = (kt + 2 < KT);

        f16x8 afk0[4], afk1[4], buk0[4], buk1[4];
#pragma unroll
        for (int mf = 0; mf < 4; mf++)
            afk0[mf] = *(const f16x8*)&Ac[(wm * 64 + mf * 16 + ln15) * 64 + sl0];
#pragma unroll
        for (int nf = 0; nf < 4; nf++)
            buk0[nf] = *(const f16x8*)&Uc[(wn * 64 + nf * 16 + ln15) * 64 + sl0];
        if (s1) STG_A4(kt + 1);
        BAR(); LGK0(); PRIO(1);
#pragma unroll
        for (int mf = 0; mf < 4; mf++)
#pragma unroll
            for (int nf = 0; nf < 4; nf++)
                MFMA(accU[mf][nf], afk0[mf], buk0[nf]);
        PRIO(0); BAR();

#pragma unroll
        for (int mf = 0; mf < 4; mf++)
            afk1[mf] = *(const f16x8*)&Ac[(wm * 64 + mf * 16 + ln15) * 64 + sl1];
#pragma unroll
        for (int nf = 0; nf < 4; nf++)
            buk1[nf] = *(const f16x8*)&Uc[(wn * 64 + nf * 16 + ln15) * 64 + sl1];
        if (s1) STG_U2(kt + 1);
        BAR(); LGK0(); PRIO(1);
#pragma unroll
        for (int mf = 0; mf < 4; mf++)
#pragma unroll
            for (int nf = 0; nf < 4; nf++)
                MFMA(accU[mf][nf], afk1[mf], buk1[nf]);
        PRIO(0); BAR();

        f16x8 bgk0[4], bgk1[4];
#pragma unroll
        for (int nf = 0; nf < 4; nf++){
            bgk0[nf] = *(const f16x8*)&Gc[(wn * 64 + nf * 16 + ln15) * 64 + sl0];
            bgk1[nf] = *(const f16x8*)&Gc[(wn * 64 + nf * 16 + ln15) * 64 + sl1];
        }
        if (s2) STG_G3(kt + 2);
        BAR(); LGK0(); PRIO(1);
#pragma unroll
        for (int mf = 0; mf < 4; mf++)
#pragma unroll
            for (int nf = 0; nf < 4; nf++)
                MFMA(accG[mf][nf], afk0[mf], bgk0[nf]);
        PRIO(0); BAR();

        PRIO(1);
#pragma unroll
        for (int mf = 0; mf < 4; mf++)
#pragma unroll
            for (int nf = 0; nf < 4; nf++)
                MFMA(accG[mf][nf], afk1[mf], bgk1[nf]);
        PRIO(0);
        if (s1){
            if (s2) asm volatile("s_waitcnt vmcnt(2)" ::: "memory");
            else    asm volatile("s_waitcnt vmcnt(0)" ::: "memory");
            BAR();
            __builtin_amdgcn_sched_barrier(0);
        }
    }
#undef STG_A4
#undef STG_U2
#undef STG_G3

    // epilogue: atomicAdd both halves into fp32 C (2-way contention max)
#pragma unroll
    for (int mf = 0; mf < 4; mf++){
        int rowb = m0 + wm * 64 + mf * 16 + lq * 4;
#pragma unroll
        for (int nf = 0; nf < 4; nf++){
            int colU = n0 + wn * 64 + nf * 16 + ln15;
            int colG = colU + 128;
            float scu = sc[colU], scg = sc[colG];
#pragma unroll
            for (int rr2 = 0; rr2 < 4; rr2++){
                atomicAdd(&C[(size_t)(rowb + rr2) * N + colU], accU[mf][nf][rr2] * scu);
                atomicAdd(&C[(size_t)(rowb + rr2) * N + colG], accG[mf][nf][rr2] * scg);
            }
        }
    }
}

// ---- gemm_small: BM=128, BN=256, per-wave 64x64, A+B 3-buf (R10 structure) ----
// EPI: 0 = store f16; 1 = fp32 +=; 3 = qkv scatter with fused RoPE (q,k)
template<int EPI>
__global__ __launch_bounds__(512, 2)
void gemm_small(const _Float16* __restrict__ A, const _Float16* __restrict__ W,
                const float* __restrict__ sc0, const float* __restrict__ sc1,
                const float* __restrict__ sc2,
                void* __restrict__ C0, void* __restrict__ C1, void* __restrict__ C2,
                const float2* __restrict__ rt,
                int MT, int NT, int N, int K)
{
    __shared__ __align__(16) _Float16 AS[3][128 * 64];
    __shared__ __align__(16) _Float16 BS[3][256 * 64];

    int nwg = MT * NT;
    int flat = blockIdx.x;
    int q = nwg >> 3, r = nwg & 7;
    int xcd = flat & 7, lid = flat >> 3;
    int swz = (xcd < r ? xcd * (q + 1) : r * (q + 1) + (xcd - r) * q) + lid;
    int bm = swz % MT, bn = swz / MT;
    int m0 = bm * 128, n0 = bn * 256;

    const int t = threadIdx.x;
    const int lane = t & 63, wid = t >> 6;
    const int ln15 = lane & 15, lq = lane >> 4;
    const int wm = wid >> 2, wn = wid & 3;
    const int sw = ln15 & 7;
    const int sl0 = (lq ^ sw) * 8, sl1 = ((4 + lq) ^ sw) * 8;

    const _Float16* srcA[2]; const _Float16* srcB[4];
#pragma unroll
    for (int rr = 0; rr < 2; rr++){
        int ch = rr * 512 + t;
        int row = ch >> 3, s = (ch & 7) ^ (row & 7);
        srcA[rr] = A + (size_t)(m0 + row) * K + s * 8;
    }
#pragma unroll
    for (int rr = 0; rr < 4; rr++){
        int ch = rr * 512 + t;
        int row = ch >> 3, s = (ch & 7) ^ (row & 7);
        srcB[rr] = W + (size_t)(n0 + row) * K + s * 8;
    }
#define STG_A3(tile) do{ int _b = (tile) % 3; \
    gload16(srcA[0] + (size_t)(tile)*64, &AS[_b][(wid*64)*8]); \
    gload16(srcA[1] + (size_t)(tile)*64, &AS[_b][(512 + wid*64)*8]); }while(0)
#define STG_B3(tile) do{ int _b = (tile) % 3; \
    gload16(srcB[0] + (size_t)(tile)*64, &BS[_b][(wid*64)*8]); \
    gload16(srcB[1] + (size_t)(tile)*64, &BS[_b][(512 + wid*64)*8]); \
    gload16(srcB[2] + (size_t)(tile)*64, &BS[_b][(1024 + wid*64)*8]); \
    gload16(srcB[3] + (size_t)(tile)*64, &BS[_b][(1536 + wid*64)*8]); }while(0)

    f32x4 acc[4][4];
#pragma unroll
    for (int i = 0; i < 4; i++)
#pragma unroll
        for (int j = 0; j < 4; j++) acc[i][j] = (f32x4){0.f, 0.f, 0.f, 0.f};

    const int KT = K >> 6;

    STG_A3(0); STG_B3(0); STG_A3(1); STG_B3(1);
    asm volatile("s_waitcnt vmcnt(6)" ::: "memory");
    BAR();

    for (int kt = 0; kt < KT; ++kt){
        int cur = kt % 3;
        const _Float16* Ac = AS[cur];
        const _Float16* Bc = BS[cur];
        bool s1 = (kt + 1 < KT), s2 = (kt + 2 < KT);

        f16x8 af0[4], af1[4], bk0[4], bk1[4];
#pragma unroll
        for (int mf = 0; mf < 4; mf++)
            af0[mf] = *(const f16x8*)&Ac[(wm * 64 + mf * 16 + ln15) * 64 + sl0];
#pragma unroll
        for (int nf = 0; nf < 4; nf++)
            bk0[nf] = *(const f16x8*)&Bc[(wn * 64 + nf * 16 + ln15) * 64 + sl0];
        if (s2) STG_B3(kt + 2);
        BAR(); LGK0(); PRIO(1);
#pragma unroll
        for (int mf = 0; mf < 4; mf++)
#pragma unroll
            for (int nf = 0; nf < 4; nf++)
                MFMA(acc[mf][nf], af0[mf], bk0[nf]);
        PRIO(0); BAR();

#pragma unroll
        for (int mf = 0; mf < 4; mf++)
            af1[mf] = *(const f16x8*)&Ac[(wm * 64 + mf * 16 + ln15) * 64 + sl1];
#pragma unroll
        for (int nf = 0; nf < 4; nf++)
            bk1[nf] = *(const f16x8*)&Bc[(wn * 64 + nf * 16 + ln15) * 64 + sl1];
        if (s2) STG_A3(kt + 2);
        BAR(); LGK0(); PRIO(1);
#pragma unroll
        for (int mf = 0; mf < 4; mf++)
#pragma unroll
            for (int nf = 0; nf < 4; nf++)
                MFMA(acc[mf][nf], af1[mf], bk1[nf]);
        PRIO(0);
        if (s1){
            if (s2) asm volatile("s_waitcnt vmcnt(6)" ::: "memory");
            else    asm volatile("s_waitcnt vmcnt(0)" ::: "memory");
            BAR();
            __builtin_amdgcn_sched_barrier(0);
        }
    }
#undef STG_A3
#undef STG_B3

    if (EPI == 3){
        const float* sp; _Float16* dp; int nloc, nstr;
        if (n0 < 2048)      { sp = sc0; dp = (_Float16*)C0; nloc = n0;        nstr = 2048; }
        else if (n0 < 2560) { sp = sc1; dp = (_Float16*)C1; nloc = n0 - 2048; nstr = 512; }
        else                { sp = sc2; dp = (_Float16*)C2; nloc = n0 - 2560; nstr = 512; }
        bool dorope = (n0 < 2560);      // q and k get RoPE, v does not
        if (dorope){
#pragma unroll
            for (int mf = 0; mf < 4; mf++){
                int rowb = m0 + wm * 64 + mf * 16 + lq * 4;
#pragma unroll
                for (int nf = 0; nf < 2; nf++){
                    int colg = wn * 64 + nf * 16 + ln15;
                    int d = nf * 16 + ln15;          // 0..31
                    float s1v = sp[nloc + colg], s2v = sp[nloc + colg + 32];
#pragma unroll
                    for (int rr2 = 0; rr2 < 4; rr2++){
                        int row = rowb + rr2;
                        int pos = row & (SEQ - 1);
                        float2 cs = rt[pos * 32 + d];
                        float x1 = acc[mf][nf][rr2] * s1v;
                        float x2 = acc[mf][nf + 2][rr2] * s2v;
                        dp[(size_t)row * nstr + nloc + colg]      = (_Float16)(x1 * cs.x - x2 * cs.y);
                        dp[(size_t)row * nstr + nloc + colg + 32] = (_Float16)(x1 * cs.y + x2 * cs.x);
                    }
                }
            }
        } else {
#pragma unroll
            for (int mf = 0; mf < 4; mf++){
                int rowb = m0 + wm * 64 + mf * 16 + lq * 4;
#pragma unroll
                for (int nf = 0; nf < 4; nf++){
                    int colg = wn * 64 + nf * 16 + ln15;
                    float sc = sp[nloc + colg];
#pragma unroll
                    for (int rr2 = 0; rr2 < 4; rr2++)
                        dp[(size_t)(rowb + rr2) * nstr + nloc + colg] =
                            (_Float16)(acc[mf][nf][rr2] * sc);
                }
            }
        }
    } else {
#pragma unroll
        for (int mf = 0; mf < 4; mf++){
            int rowb = m0 + wm * 64 + mf * 16 + lq * 4;
#pragma unroll
            for (int nf = 0; nf < 4; nf++){
                int colg = n0 + wn * 64 + nf * 16 + ln15;
                float sc = sc0[colg];
#pragma unroll
                for (int rr2 = 0; rr2 < 4; rr2++){
                    size_t idx = (size_t)(rowb + rr2) * N + colg;
                    float val = acc[mf][nf][rr2] * sc;
                    if (EPI == 0){
                        ((_Float16*)C0)[idx] = (_Float16)val;
                    } else {
                        ((float*)C0)[idx] += val;
                    }
                }
            }
        }
    }
}

// ---------------- flash attention (causal, GQA 4:1, fp16) ----------------
__global__ __launch_bounds__(256)
void attn_kernel(const _Float16* __restrict__ Qb, const _Float16* __restrict__ Kb,
                 const _Float16* __restrict__ Vb, _Float16* __restrict__ Ob)
{
    int bid = blockIdx.x;
    int qt = bid >> 7, h = bid & 31, b = (bid >> 5) & 3;
    int kvh = h >> 2;
    int q0 = qt * 128;
    int t = threadIdx.x, lane = t & 63, wid = t >> 6;
    int ln15 = lane & 15, lq = lane >> 4;

    __shared__ __align__(16) _Float16 Ksm[64 * 72];
    __shared__ __align__(16) _Float16 Vt[64 * 72];
    __shared__ __align__(16) _Float16 Pl[128 * 72];

    f16x8 qf[2][2];
    int qrow_g = b * SEQ + q0 + wid * 32;
#pragma unroll
    for (int mf = 0; mf < 2; mf++)
#pragma unroll
        for (int dc = 0; dc < 2; dc++)
            qf[mf][dc] = *(const f16x8*)(Qb + (size_t)(qrow_g + mf * 16 + ln15) * D_MODEL
                                         + h * HDIM + dc * 32 + lq * 8);

    f32x4 outv[2][4];
#pragma unroll
    for (int i = 0; i < 2; i++)
#pragma unroll
        for (int j = 0; j < 4; j++) outv[i][j] = (f32x4){0.f, 0.f, 0.f, 0.f};
    float mrun[2][4], lrun[2][4];
#pragma unroll
    for (int i = 0; i < 2; i++)
#pragma unroll
        for (int r = 0; r < 4; r++){ mrun[i][r] = -1e30f; lrun[i][r] = 0.f; }

    int ntile = (q0 + 128) >> 6;
    int ld_row = (t + 0) >> 3, ld_c8 = t & 7;
    int ld_row1 = (t + 256) >> 3;

    f16x8 k8[2], v8[2];
    {
        size_t base0 = (size_t)(b * SEQ + ld_row) * DKV + kvh * HDIM + ld_c8 * 8;
        size_t base1 = (size_t)(b * SEQ + ld_row1) * DKV + kvh * HDIM + ld_c8 * 8;
        k8[0] = *(const f16x8*)&Kb[base0];  v8[0] = *(const f16x8*)&Vb[base0];
        k8[1] = *(const f16x8*)&Kb[base1];  v8[1] = *(const f16x8*)&Vb[base1];
    }

    for (int kt = 0; kt < ntile; kt++){
        __syncthreads();
#pragma unroll
        for (int i = 0; i < 2; i++){
            int row = (i == 0) ? ld_row : ld_row1;
            *(f16x8*)&Ksm[row * 72 + ld_c8 * 8] = k8[i];
#pragma unroll
            for (int j = 0; j < 8; j++)
                Vt[(ld_c8 * 8 + j) * 72 + row] = v8[i][j];
        }
        __syncthreads();

        if (kt + 1 < ntile){
            size_t base0 = (size_t)(b * SEQ + (kt + 1) * 64 + ld_row) * DKV + kvh * HDIM + ld_c8 * 8;
            size_t base1 = (size_t)(b * SEQ + (kt + 1) * 64 + ld_row1) * DKV + kvh * HDIM + ld_c8 * 8;
            k8[0] = *(const f16x8*)&Kb[base0];  v8[0] = *(const f16x8*)&Vb[base0];
            k8[1] = *(const f16x8*)&Kb[base1];  v8[1] = *(const f16x8*)&Vb[base1];
        }

#pragma unroll
        for (int mf = 0; mf < 2; mf++){
            f32x4 sa[4];
#pragma unroll
            for (int kvf = 0; kvf < 4; kvf++) sa[kvf] = (f32x4){0.f, 0.f, 0.f, 0.f};
#pragma unroll
            for (int kvf = 0; kvf < 4; kvf++)
#pragma unroll
                for (int dc = 0; dc < 2; dc++){
                    f16x8 kb = *(const f16x8*)&Ksm[(kvf * 16 + ln15) * 72 + dc * 32 + lq * 8];
                    sa[kvf] = __builtin_amdgcn_mfma_f32_16x16x32_f16(qf[mf][dc], kb, sa[kvf], 0, 0, 0);
                }
            int qbase = q0 + wid * 32 + mf * 16 + lq * 4;
            float rowmax[4] = {-1e30f, -1e30f, -1e30f, -1e30f};
#pragma unroll
            for (int kvf = 0; kvf < 4; kvf++){
                int kva = kt * 64 + kvf * 16 + ln15;
#pragma unroll
                for (int r = 0; r < 4; r++){
                    float sv = sa[kvf][r] * 0.125f;
                    if (kva > qbase + r) sv = -1e9f;
                    sa[kvf][r] = sv;
                    rowmax[r] = fmaxf(rowmax[r], sv);
                }
            }
#pragma unroll
            for (int r = 0; r < 4; r++){
                rowmax[r] = fmaxf(rowmax[r], __shfl_xor(rowmax[r], 1, 64));
                rowmax[r] = fmaxf(rowmax[r], __shfl_xor(rowmax[r], 2, 64));
                rowmax[r] = fmaxf(rowmax[r], __shfl_xor(rowmax[r], 4, 64));
                rowmax[r] = fmaxf(rowmax[r], __shfl_xor(rowmax[r], 8, 64));
            }
            float scl[4], rsum[4];
#pragma unroll
            for (int r = 0; r < 4; r++){
                float mo = mrun[mf][r];
                float mn = fmaxf(mo, rowmax[r]);
                scl[r] = expf(mo - mn);
                mrun[mf][r] = mn;
                rsum[r] = 0.f;
            }
#pragma unroll
            for (int kvf = 0; kvf < 4; kvf++)
#pragma unroll
                for (int r = 0; r < 4; r++){
                    float p = expf(sa[kvf][r] - mrun[mf][r]);
                    sa[kvf][r] = p;
                    rsum[r] += p;
                }
#pragma unroll
            for (int r = 0; r < 4; r++){
                rsum[r] += __shfl_xor(rsum[r], 1, 64);
                rsum[r] += __shfl_xor(rsum[r], 2, 64);
                rsum[r] += __shfl_xor(rsum[r], 4, 64);
                rsum[r] += __shfl_xor(rsum[r], 8, 64);
                lrun[mf][r] = lrun[mf][r] * scl[r] + rsum[r];
            }
#pragma unroll
            for (int dfr = 0; dfr < 4; dfr++)
#pragma unroll
                for (int r = 0; r < 4; r++) outv[mf][dfr][r] *= scl[r];
#pragma unroll
            for (int kvf = 0; kvf < 4; kvf++)
#pragma unroll
                for (int r = 0; r < 4; r++)
                    Pl[(wid * 32 + mf * 16 + lq * 4 + r) * 72 + kvf * 16 + ln15] = (_Float16)sa[kvf][r];
        }
        __syncthreads();

#pragma unroll
        for (int mf = 0; mf < 2; mf++)
#pragma unroll
            for (int kc = 0; kc < 2; kc++){
                f16x8 pa = *(const f16x8*)&Pl[(wid * 32 + mf * 16 + ln15) * 72 + kc * 32 + lq * 8];
#pragma unroll
                for (int dfr = 0; dfr < 4; dfr++){
                    f16x8 vb = *(const f16x8*)&Vt[(dfr * 16 + ln15) * 72 + kc * 32 + lq * 8];
                    outv[mf][dfr] = __builtin_amdgcn_mfma_f32_16x16x32_f16(pa, vb, outv[mf][dfr], 0, 0, 0);
                }
            }
    }

#pragma unroll
    for (int mf = 0; mf < 2; mf++)
#pragma unroll
        for (int dfr = 0; dfr < 4; dfr++)
#pragma unroll
            for (int r = 0; r < 4; r++){
                float val = outv[mf][dfr][r] / lrun[mf][r];
                size_t row = (size_t)(b * SEQ + q0 + wid * 32 + mf * 16 + lq * 4 + r);
                Ob[row * D_MODEL + h * HDIM + dfr * 16 + ln15] = (_Float16)val;
            }
}

// ---------------- LM head: out[b][v] = xf[b] . embed[v] ----------------
__global__ __launch_bounds__(256)
void lmhead_kernel(const float* __restrict__ XF, const float* __restrict__ embed,
                   float* __restrict__ out)
{
    __shared__ float xl[4 * D_MODEL];
    int t = threadIdx.x;
#pragma unroll
    for (int i = 0; i < 8; i++){
        int f = t + i * 256;
        ((float4*)xl)[f] = ((const float4*)XF)[f];
    }
    __syncthreads();
    int lane = t & 63, wid = t >> 6;
    for (int rr = 0; rr < 16; rr++){
        int vrow = blockIdx.x * 64 + wid * 16 + rr;
        const float4* er = (const float4*)(embed + (size_t)vrow * D_MODEL);
        float acc[4] = {0.f, 0.f, 0.f, 0.f};
        for (int j = 0; j < 8; j++){
            float4 e = er[lane + 64 * j];
#pragma unroll
            for (int b = 0; b < 4; b++){
                float4 xv = ((float4*)xl)[b * 512 + lane + 64 * j];
                acc[b] += e.x * xv.x + e.y * xv.y + e.z * xv.z + e.w * xv.w;
            }
        }
#pragma unroll
        for (int b = 0; b < 4; b++)
            for (int off = 32; off; off >>= 1) acc[b] += __shfl_xor(acc[b], off, 64);
        if (lane == 0){
#pragma unroll
            for (int b = 0; b < 4; b++)
                out[(size_t)b * VOCAB + vrow] = acc[b];
        }
    }
}

extern "C" void kernel_launch(void* const* d_in, const int* in_sizes, int n_in,
                              void* d_out, int out_size, void* d_ws, size_t ws_size,
                              hipStream_t stream)
{
    const int*   tok   = (const int*)d_in[0];
    const float* embed = (const float*)d_in[1];
    const float* g_attn = (const float*)d_in[2];
    const float* g_mlp  = (const float*)d_in[3];
    const float* g_fin  = (const float*)d_in[4];
    const int*   wq = (const int*)d_in[5];  const float* sq = (const float*)d_in[6];
    const int*   wk = (const int*)d_in[7];  const float* sk = (const float*)d_in[8];
    const int*   wv = (const int*)d_in[9];  const float* sv = (const float*)d_in[10];
    const int*   wo = (const int*)d_in[11]; const float* so = (const float*)d_in[12];
    const int*   wg = (const int*)d_in[13]; const float* sg = (const float*)d_in[14];
    const int*   wu = (const int*)d_in[15]; const float* su = (const float*)d_in[16];
    const int*   wd = (const int*)d_in[17]; const float* sd = (const float*)d_in[18];
    float* out = (float*)d_out;

    char* p = (char*)d_ws;
    _Float16* Wf = (_Float16*)p;  p += (size_t)60817408 * 2;   // per-layer fp16 weights
    float*    X  = (float*)p;     p += (size_t)NTOK * D_MODEL * 4;
    _Float16* Hb = (_Float16*)p;  p += (size_t)NTOK * D_MODEL * 2;
    _Float16* Qb = (_Float16*)p;  p += (size_t)NTOK * D_MODEL * 2;
    _Float16* Kb = (_Float16*)p;  p += (size_t)NTOK * DKV * 2;
    _Float16* Vb = (_Float16*)p;  p += (size_t)NTOK * DKV * 2;
    _Float16* Ab = (_Float16*)p;  p += (size_t)NTOK * D_MODEL * 2;
    _Float16* Ub = (_Float16*)p;  p += (size_t)NTOK * DFF * 2;
    float*    XF = (float*)p;     p += (size_t)BATCH * D_MODEL * 4;
    float2*   RT = (float2*)p;    p += (size_t)SEQ * 32 * 8;    // rope table

    _Float16* wqf = Wf;                                   // [2048 x 2048]
    _Float16* wkf = wqf + (size_t)D_MODEL * D_MODEL;      // [512 x 2048]
    _Float16* wvf = wkf + (size_t)DKV * D_MODEL;          // [512 x 2048]
    _Float16* wof = wvf + (size_t)DKV * D_MODEL;
    _Float16* wgf = wof + (size_t)D_MODEL * D_MODEL;
    _Float16* wuf = wgf + (size_t)DFF * D_MODEL;
    _Float16* wdf = wuf + (size_t)DFF * D_MODEL;

    gather_kernel<<<NTOK, 256, 0, stream>>>(tok, embed, X);
    rope_table_kernel<<<SEQ * 32 / 256, 256, 0, stream>>>(RT);

    for (int l = 0; l < NLAYER; l++){
        wconv_all_kernel<<<15204352 / 256, 256, 0, stream>>>(
            wq + (size_t)l * D_MODEL * D_MODEL,
            wk + (size_t)l * DKV * D_MODEL,
            wv + (size_t)l * DKV * D_MODEL,
            wo + (size_t)l * D_MODEL * D_MODEL,
            wg + (size_t)l * DFF * D_MODEL,
            wu + (size_t)l * DFF * D_MODEL,
            wd + (size_t)l * D_MODEL * DFF,
            Wf);

        rmsnorm_kernel<<<NTOK, 256, 0, stream>>>(X, g_attn + (size_t)l * D_MODEL, Hb);
        gemm_small<3><<<32 * 12, 512, 0, stream>>>(Hb, wqf,
            sq + (size_t)l * D_MODEL, sk + (size_t)l * DKV, sv + (size_t)l * DKV,
            Qb, Kb, Vb, RT, 32, 12, 3072, D_MODEL);
        attn_kernel<<<1024, 256, 0, stream>>>(Qb, Kb, Vb, Ab);
        gemm_small<1><<<32 * 8, 512, 0, stream>>>(Ab, wof,
            so + (size_t)l * D_MODEL, nullptr, nullptr,
            X, nullptr, nullptr, nullptr, 32, 8, D_MODEL, D_MODEL);

        rmsnorm_kernel<<<NTOK, 256, 0, stream>>>(X, g_mlp + (size_t)l * D_MODEL, Hb);
        gemm_mlp<<<16 * 64, 512, 0, stream>>>(Hb, wuf, wgf,
            su + (size_t)l * DFF, sg + (size_t)l * DFF, Ub, 16, 64, D_MODEL);
        // wd: split-K2 dual-panel (mlp-density), atomicAdd into fp32 X
        gemm_wd<<<16 * 8 * 2, 512, 0, stream>>>(Ub, wdf,
            sd + (size_t)l * D_MODEL, X, 16, 8, D_MODEL, DFF);
    }

    final_norm_kernel<<<BATCH, 256, 0, stream>>>(X, g_fin, XF);
    lmhead_kernel<<<VOCAB / 64, 256, 0, stream>>>(XF, embed, out);
}